// Round 1
// baseline (1976.649 us; speedup 1.0000x reference)
//
#include <hip/hip_runtime.h>
#include <math.h>

#define NB 16      // B
#define NN 1024    // N
#define NF 32      // F
#define NT 12      // T
#define NFC 64
#define NFT 64

// ---------------- temporal attention ----------------

// lhs_pre[b][t][f] = sum_n x[b,n,f,t]*U1[n]   (atomic-accumulated over n-chunks)
__global__ __launch_bounds__(384) void k_lhspre(const float* __restrict__ x,
                                                const float* __restrict__ U1,
                                                float* __restrict__ lhs_pre)
{
    int b = blockIdx.x, ch = blockIdx.y, tid = threadIdx.x;
    int f = tid / 12, t = tid - f * 12;
    float acc = 0.f;
    int n0 = ch * 32;
    for (int n = n0; n < n0 + 32; n++)
        acc += x[((size_t)(b * NN + n)) * 384 + tid] * U1[n];
    atomicAdd(&lhs_pre[b * 384 + t * 32 + f], acc);
}

// rhs[b][n][t] = sum_f U3[f]*x[b,n,f,t]
__global__ __launch_bounds__(384) void k_rhs(const float* __restrict__ x,
                                             const float* __restrict__ U3,
                                             float* __restrict__ rhs)
{
    __shared__ float sm[8 * 384];
    int tid = threadIdx.x;
    size_t r0 = (size_t)blockIdx.x * 8;
    for (int i = 0; i < 8; i++) sm[i * 384 + tid] = x[(r0 + i) * 384 + tid];
    __syncthreads();
    if (tid < 96) {
        int i = tid / 12, t = tid - i * 12;
        float s = 0.f;
        for (int f = 0; f < 32; f++) s += U3[f] * sm[i * 384 + f * 12 + t];
        rhs[(r0 + i) * 12 + t] = s;
    }
}

// lhs[b][t][n] = sum_f lhs_pre[b][t][f]*U2[f][n]
__global__ __launch_bounds__(256) void k_lhs(const float* __restrict__ lhs_pre,
                                             const float* __restrict__ U2,
                                             float* __restrict__ lhs)
{
    int bt = blockIdx.x;  // b*12+t
    int tid = threadIdx.x;
    __shared__ float lp[32];
    if (tid < 32) lp[tid] = lhs_pre[bt * 32 + tid];
    __syncthreads();
    for (int q = 0; q < 4; q++) {
        int n = q * 256 + tid;
        float a = 0.f;
        for (int f = 0; f < 32; f++) a += lp[f] * U2[f * NN + n];
        lhs[(size_t)bt * NN + n] = a;
    }
}

// prod[b][s][u] = sum_n lhs[b,s,n]*rhs[b,n,u]
__global__ __launch_bounds__(64) void k_prod(const float* __restrict__ lhs,
                                             const float* __restrict__ rhs,
                                             float* __restrict__ prod)
{
    int blk = blockIdx.x;
    int b = blk / 144, r = blk - b * 144;
    int s = r / 12, u = r - s * 12;
    int tid = threadIdx.x;
    float p = 0.f;
    for (int n = tid; n < NN; n += 64)
        p += lhs[((size_t)b * 12 + s) * NN + n] * rhs[((size_t)b * NN + n) * 12 + u];
    for (int o = 32; o > 0; o >>= 1) p += __shfl_xor(p, o);
    if (tid == 0) prod[blk] = p;
}

// E[b][t][u]: E0 = Ve @ sigmoid(prod+be); softmax over t
__global__ __launch_bounds__(192) void k_E(const float* __restrict__ prod,
                                           const float* __restrict__ be,
                                           const float* __restrict__ Ve,
                                           float* __restrict__ E)
{
    int b = blockIdx.x, tid = threadIdx.x;
    __shared__ float ssig[144], sE[144], mx[12], sm[12];
    if (tid < 144) ssig[tid] = 1.f / (1.f + expf(-(prod[b * 144 + tid] + be[tid])));
    __syncthreads();
    if (tid < 144) {
        int t = tid / 12, u = tid - t * 12;
        float a = 0.f;
        for (int s2 = 0; s2 < 12; s2++) a += Ve[t * 12 + s2] * ssig[s2 * 12 + u];
        sE[tid] = a;
    }
    __syncthreads();
    if (tid < 12) {
        float m = -1e30f;
        for (int t = 0; t < 12; t++) m = fmaxf(m, sE[t * 12 + tid]);
        float s = 0.f;
        for (int t = 0; t < 12; t++) s += expf(sE[t * 12 + tid] - m);
        mx[tid] = m; sm[tid] = s;
    }
    __syncthreads();
    if (tid < 144) {
        int u = tid % 12;
        E[b * 144 + tid] = expf(sE[tid] - mx[u]) / sm[u];
    }
}

// x_TAt[b][n][f][u] = sum_t x[b,n,f,t]*E[b,t,u]
__global__ __launch_bounds__(384) void k_xTAt(const float* __restrict__ x,
                                              const float* __restrict__ E,
                                              float* __restrict__ xT)
{
    __shared__ float xs[8 * 384], Es[144];
    int b = blockIdx.y, tid = threadIdx.x;
    size_t r0 = (size_t)b * NN + (size_t)blockIdx.x * 8;
    if (tid < 144) Es[tid] = E[b * 144 + tid];
    for (int i = 0; i < 8; i++) xs[i * 384 + tid] = x[(r0 + i) * 384 + tid];
    __syncthreads();
    int f = tid / 12, u = tid - f * 12;
    for (int i = 0; i < 8; i++) {
        float a = 0.f;
#pragma unroll
        for (int t = 0; t < 12; t++) a += xs[i * 384 + f * 12 + t] * Es[t * 12 + u];
        xT[(r0 + i) * 384 + f * 12 + u] = a;
    }
}

// ---------------- spatial attention ----------------

// l2[b][n][t], r2[b][t][n] from x_TAt
__global__ __launch_bounds__(384) void k_l2r2(const float* __restrict__ xT,
                                              const float* __restrict__ W1,
                                              const float* __restrict__ W2,
                                              const float* __restrict__ W3,
                                              float* __restrict__ l2,
                                              float* __restrict__ r2)
{
    __shared__ float xs[8 * 384];
    __shared__ float lp[8][32];
    int b = blockIdx.y, tid = threadIdx.x;
    int n0 = blockIdx.x * 8;
    size_t r0 = (size_t)b * NN + n0;
    for (int i = 0; i < 8; i++) xs[i * 384 + tid] = xT[(r0 + i) * 384 + tid];
    __syncthreads();
    if (tid < 256) {
        int i = tid >> 5, f = tid & 31;
        float a = 0.f;
#pragma unroll
        for (int t = 0; t < 12; t++) a += xs[i * 384 + f * 12 + t] * W1[t];
        lp[i][f] = a;
    }
    __syncthreads();
    if (tid < 96) {
        int i = tid / 12, t = tid - i * 12;
        float a = 0.f, rr = 0.f;
        for (int f = 0; f < 32; f++) {
            a += lp[i][f] * W2[f * 12 + t];
            rr += W3[f] * xs[i * 384 + f * 12 + t];
        }
        l2[(r0 + i) * 12 + t] = a;
        r2[((size_t)b * 12 + t) * NN + n0 + i] = rr;
    }
}

// P[b][m][k] = sigmoid(sum_t l2[b,m,t]*r2[b,t,k] + bs[m,k])
__global__ __launch_bounds__(256) void k_P(const float* __restrict__ l2,
                                           const float* __restrict__ r2,
                                           const float* __restrict__ bs,
                                           float* __restrict__ P)
{
    int b = blockIdx.z, m = blockIdx.y;
    int k = blockIdx.x * 256 + threadIdx.x;
    float lv[12];
#pragma unroll
    for (int t = 0; t < 12; t++) lv[t] = l2[((size_t)b * NN + m) * 12 + t];
    float p = 0.f;
#pragma unroll
    for (int t = 0; t < 12; t++) p += lv[t] * r2[((size_t)b * 12 + t) * NN + k];
    p += bs[(size_t)m * NN + k];
    P[((size_t)b * NN + m) * NN + k] = 1.f / (1.f + expf(-p));
}

// ---------------- generic fp32 GEMM: C[bz][i][j] = alpha*sum_k A[i][k]*B[bz][k][j] (-I opt) ----------------
__global__ __launch_bounds__(256) void gemm_s(const float* __restrict__ A,
                                              const float* __restrict__ Bm,
                                              float* __restrict__ C,
                                              int Kd, int ldA, int ldB, int ldC,
                                              long sB, long sC, float alpha, int subI)
{
    int bz = blockIdx.z;
    const float* Bb = Bm + (size_t)bz * sB;
    float* Cb = C + (size_t)bz * sC;
    int i0 = blockIdx.y * 64, j0 = blockIdx.x * 64;
    __shared__ float As[16][64];  // [k][i]
    __shared__ float Bs[16][64];  // [k][j]
    int tid = threadIdx.x;
    int tx = tid & 15, ty = tid >> 4;
    int ar = tid >> 2, ac = (tid & 3) << 2;
    int br = tid >> 4, bc = (tid & 15) << 2;
    float acc[4][4];
#pragma unroll
    for (int ii = 0; ii < 4; ii++)
#pragma unroll
        for (int jj = 0; jj < 4; jj++) acc[ii][jj] = 0.f;
    for (int k0 = 0; k0 < Kd; k0 += 16) {
        float4 av = *(const float4*)(A + (size_t)(i0 + ar) * ldA + k0 + ac);
        float4 bv = *(const float4*)(Bb + (size_t)(k0 + br) * ldB + j0 + bc);
        As[ac + 0][ar] = av.x; As[ac + 1][ar] = av.y;
        As[ac + 2][ar] = av.z; As[ac + 3][ar] = av.w;
        *(float4*)(&Bs[br][bc]) = bv;
        __syncthreads();
#pragma unroll
        for (int kk = 0; kk < 16; kk++) {
            float a[4], bf[4];
#pragma unroll
            for (int ii = 0; ii < 4; ii++) a[ii] = As[kk][ii * 16 + ty];
#pragma unroll
            for (int jj = 0; jj < 4; jj++) bf[jj] = Bs[kk][jj * 16 + tx];
#pragma unroll
            for (int ii = 0; ii < 4; ii++)
#pragma unroll
                for (int jj = 0; jj < 4; jj++) acc[ii][jj] += a[ii] * bf[jj];
        }
        __syncthreads();
    }
#pragma unroll
    for (int ii = 0; ii < 4; ii++)
#pragma unroll
        for (int jj = 0; jj < 4; jj++) {
            int gi = i0 + ii * 16 + ty, gj = j0 + jj * 16 + tx;
            float v = alpha * acc[ii][jj];
            if (subI && gi == gj) v -= 1.f;
            Cb[(size_t)gi * ldC + gj] = v;
        }
}

// H[b][m][j] = sum_n G[n][m]*spat[b][n][m]*X[b][n][j]   (j = f*12+t, 384 wide)
__global__ __launch_bounds__(256) void gemm_h(const float* __restrict__ G,
                                              const float* __restrict__ spat,
                                              const float* __restrict__ X,
                                              float* __restrict__ H)
{
    int b = blockIdx.z;
    int m0 = blockIdx.y * 64, j0 = blockIdx.x * 64;
    const float* sp = spat + (size_t)b * NN * NN;
    const float* Xb = X + (size_t)b * NN * 384;
    __shared__ float As[16][64];  // [n][m]
    __shared__ float Bs[16][64];  // [n][j]
    int tid = threadIdx.x, tx = tid & 15, ty = tid >> 4;
    int r = tid >> 4, c = (tid & 15) << 2;
    float acc[4][4];
#pragma unroll
    for (int ii = 0; ii < 4; ii++)
#pragma unroll
        for (int jj = 0; jj < 4; jj++) acc[ii][jj] = 0.f;
    for (int n0 = 0; n0 < NN; n0 += 16) {
        float4 g = *(const float4*)(G + (size_t)(n0 + r) * NN + m0 + c);
        float4 s = *(const float4*)(sp + (size_t)(n0 + r) * NN + m0 + c);
        float4 xv = *(const float4*)(Xb + (size_t)(n0 + r) * 384 + j0 + c);
        g.x *= s.x; g.y *= s.y; g.z *= s.z; g.w *= s.w;
        *(float4*)(&As[r][c]) = g;
        *(float4*)(&Bs[r][c]) = xv;
        __syncthreads();
#pragma unroll
        for (int kk = 0; kk < 16; kk++) {
            float a[4], bf[4];
#pragma unroll
            for (int ii = 0; ii < 4; ii++) a[ii] = As[kk][ii * 16 + ty];
#pragma unroll
            for (int jj = 0; jj < 4; jj++) bf[jj] = Bs[kk][jj * 16 + tx];
#pragma unroll
            for (int ii = 0; ii < 4; ii++)
#pragma unroll
                for (int jj = 0; jj < 4; jj++) acc[ii][jj] += a[ii] * bf[jj];
        }
        __syncthreads();
    }
#pragma unroll
    for (int ii = 0; ii < 4; ii++)
#pragma unroll
        for (int jj = 0; jj < 4; jj++)
            H[((size_t)b * NN + m0 + ii * 16 + ty) * 384 + j0 + jj * 16 + tx] = acc[ii][jj];
}

// ---------------- softmax over n (axis=1) in place + global sum ----------------
__global__ __launch_bounds__(256) void k_softmax(float* __restrict__ S, float* __restrict__ gsum)
{
    int b = blockIdx.y;
    int k0 = blockIdx.x * 64;
    int tid = threadIdx.x;
    int kx = tid & 63, ny = tid >> 6;
    float* Sb = S + (size_t)b * NN * NN;
    __shared__ float red[4][64];
    __shared__ float mcol[64], scol[64];
    float vmax = -1e30f;
    for (int n = ny; n < NN; n += 4) vmax = fmaxf(vmax, Sb[(size_t)n * NN + k0 + kx]);
    red[ny][kx] = vmax;
    __syncthreads();
    if (ny == 0) mcol[kx] = fmaxf(fmaxf(red[0][kx], red[1][kx]), fmaxf(red[2][kx], red[3][kx]));
    __syncthreads();
    float mx = mcol[kx];
    float s = 0.f;
    for (int n = ny; n < NN; n += 4) {
        size_t i = (size_t)n * NN + k0 + kx;
        float e = expf(Sb[i] - mx);
        Sb[i] = e;
        s += e;
    }
    red[ny][kx] = s;
    __syncthreads();
    if (ny == 0) scol[kx] = red[0][kx] + red[1][kx] + red[2][kx] + red[3][kx];
    __syncthreads();
    float inv = 1.f / scol[kx];
    float part = 0.f;
    for (int n = ny; n < NN; n += 4) {
        size_t i = (size_t)n * NN + k0 + kx;
        float e = Sb[i] * inv;
        Sb[i] = e;
        part += e;
    }
    for (int o = 32; o > 0; o >>= 1) part += __shfl_xor(part, o);
    __shared__ float wsum[4];
    if ((tid & 63) == 0) wsum[tid >> 6] = part;
    __syncthreads();
    if (tid == 0) atomicAdd(gsum, wsum[0] + wsum[1] + wsum[2] + wsum[3]);
}

__global__ void k_thresh(float* __restrict__ S, const float* __restrict__ gsum)
{
    float thr = (gsum[0] * (1.f / ((float)NB * NN * NN))) / 0.6f;
    size_t i = (size_t)blockIdx.x * blockDim.x + threadIdx.x;
    size_t stride = (size_t)gridDim.x * blockDim.x;
    size_t tot = (size_t)NB * NN * NN;
    for (; i < tot; i += stride) {
        float v = S[i];
        S[i] = (v < thr) ? 0.f : v;
    }
}

// ---------------- support graph ----------------
__global__ __launch_bounds__(256) void k_sup(const float* __restrict__ emb, float* __restrict__ sup)
{
    int n = blockIdx.x, tid = threadIdx.x;
    __shared__ float en[16];
    if (tid < 16) en[tid] = emb[n * 16 + tid];
    __syncthreads();
    float v[4];
#pragma unroll
    for (int q = 0; q < 4; q++) {
        int m = q * 256 + tid;
        float d = 0.f;
#pragma unroll
        for (int dd = 0; dd < 16; dd++) d += en[dd] * emb[m * 16 + dd];
        v[q] = fmaxf(d, 0.f);
    }
    float mx = fmaxf(fmaxf(v[0], v[1]), fmaxf(v[2], v[3]));
    for (int o = 32; o > 0; o >>= 1) mx = fmaxf(mx, __shfl_xor(mx, o));
    __shared__ float red[4];
    if ((tid & 63) == 0) red[tid >> 6] = mx;
    __syncthreads();
    mx = fmaxf(fmaxf(red[0], red[1]), fmaxf(red[2], red[3]));
    float e[4];
    float s = 0.f;
#pragma unroll
    for (int q = 0; q < 4; q++) { e[q] = expf(v[q] - mx); s += e[q]; }
    for (int o = 32; o > 0; o >>= 1) s += __shfl_xor(s, o);
    __shared__ float red2[4];
    if ((tid & 63) == 0) red2[tid >> 6] = s;
    __syncthreads();
    s = red2[0] + red2[1] + red2[2] + red2[3];
    float inv = 1.f / s;
#pragma unroll
    for (int q = 0; q < 4; q++) sup[(size_t)n * NN + q * 256 + tid] = e[q] * inv;
}

// ---------------- weight norm ----------------
__global__ __launch_bounds__(192) void k_wnorm(const float* __restrict__ tcv,
                                               const float* __restrict__ tcg,
                                               float* __restrict__ wn)
{
    int o = blockIdx.x, tid = threadIdx.x;
    float t = tcv[o * 192 + tid];
    float p = t * t;
    for (int off = 32; off > 0; off >>= 1) p += __shfl_xor(p, off);
    __shared__ float wsr[3];
    if ((tid & 63) == 0) wsr[tid >> 6] = p;
    __syncthreads();
    float sum = wsr[0] + wsr[1] + wsr[2];
    wn[o * 192 + tid] = t * (tcg[o] / sqrtf(sum));
}

// ---------------- fused tail: Theta contraction + relu + time conv + residual + LN ----------------
__global__ __launch_bounds__(256) void k_final(const float* __restrict__ x,
                                               const float* __restrict__ h1,
                                               const float* __restrict__ h2,
                                               const float* __restrict__ spat,
                                               const float* __restrict__ Theta,
                                               const float* __restrict__ wn,
                                               const float* __restrict__ tcb,
                                               const float* __restrict__ rcw,
                                               const float* __restrict__ rcb,
                                               const float* __restrict__ lnw,
                                               const float* __restrict__ lnb,
                                               float* __restrict__ out)
{
    int b = blockIdx.y;
    int tid = threadIdx.x;
    __shared__ float wns[64 * 195];   // [o][cd] padded stride 195 (bank spread)
    __shared__ float rcs[64 * 33];    // [o][f] padded stride 33
    __shared__ float xs[384], h1s[384], h2s[384];
    __shared__ float gcnS[768];       // [t][o]
    __shared__ float yS[768];         // [t][o]
    __shared__ float mu[12], rstd[12];
    for (int i = tid; i < 12288; i += 256) {
        int o = i / 192, cd = i - o * 192;
        wns[o * 195 + cd] = wn[i];
    }
    for (int i = tid; i < 2048; i += 256) {
        int o = i >> 5, f = i & 31;
        rcs[o * 33 + f] = rcw[i];
    }
    for (int mi = 0; mi < 8; mi++) {
        int m = blockIdx.x * 8 + mi;
        size_t row = ((size_t)b * NN + m) * 384;
        for (int i = tid; i < 384; i += 256) {
            xs[i] = x[row + i]; h1s[i] = h1[row + i]; h2s[i] = h2[row + i];
        }
        __syncthreads();
        float sd = spat[(size_t)b * NN * NN + (size_t)m * NN + m];
        // gcn = relu(sum_k h_k @ Theta_k)
        for (int idx = tid; idx < 768; idx += 256) {
            int t = idx >> 6, o = idx & 63;
            float acc = 0.f;
#pragma unroll 8
            for (int f = 0; f < 32; f++) {
                acc += (sd * xs[f * 12 + t]) * Theta[f * 64 + o]
                     + h1s[f * 12 + t] * Theta[2048 + f * 64 + o]
                     + h2s[f * 12 + t] * Theta[4096 + f * 64 + o];
            }
            gcnS[idx] = fmaxf(acc, 0.f);
        }
        __syncthreads();
        // y[t][o] = timeconv + residual
        for (int idx = tid; idx < 768; idx += 256) {
            int t = idx >> 6, o = idx & 63;
            float v = tcb[o];
            for (int dt = 0; dt < 3; dt++) {
                int tt = t + dt - 1;
                if (tt < 0 || tt >= 12) continue;
                const float* g = &gcnS[tt * 64];
                const float* w = &wns[o * 195 + dt];
                float a = 0.f;
#pragma unroll 16
                for (int c = 0; c < 64; c++) a += w[c * 3] * g[c];
                v += a;
            }
            float rr = rcb[o];
#pragma unroll 8
            for (int f = 0; f < 32; f++) rr += rcs[o * 33 + f] * xs[f * 12 + t];
            yS[idx] = v + rr;
        }
        __syncthreads();
        if (tid < 12) {
            float s = 0.f, s2 = 0.f;
            for (int o = 0; o < 64; o++) {
                float v = yS[tid * 64 + o];
                s += v; s2 += v * v;
            }
            float mm = s * (1.f / 64.f);
            float var = s2 * (1.f / 64.f) - mm * mm;
            mu[tid] = mm;
            rstd[tid] = rsqrtf(var + 1e-5f);
        }
        __syncthreads();
        size_t obase = ((size_t)b * NN + m) * 768;
        for (int idx = tid; idx < 768; idx += 256) {
            int o = idx / 12, t = idx - o * 12;
            out[obase + idx] = (yS[t * 64 + o] - mu[t]) * rstd[t] * lnw[o] + lnb[o];
        }
        __syncthreads();
    }
}

extern "C" void kernel_launch(void* const* d_in, const int* in_sizes, int n_in,
                              void* d_out, int out_size, void* d_ws, size_t ws_size,
                              hipStream_t stream)
{
    const float* x    = (const float*)d_in[0];
    const float* emb  = (const float*)d_in[1];
    const float* W1   = (const float*)d_in[2];
    const float* W2   = (const float*)d_in[3];
    const float* W3   = (const float*)d_in[4];
    const float* bs   = (const float*)d_in[5];
    const float* Vs   = (const float*)d_in[6];
    const float* U1   = (const float*)d_in[7];
    const float* U2   = (const float*)d_in[8];
    const float* U3   = (const float*)d_in[9];
    const float* be   = (const float*)d_in[10];
    const float* Ve   = (const float*)d_in[11];
    const float* Theta= (const float*)d_in[12];
    const float* tcv  = (const float*)d_in[13];
    const float* tcg  = (const float*)d_in[14];
    const float* tcb  = (const float*)d_in[15];
    const float* rcw  = (const float*)d_in[16];
    const float* rcb  = (const float*)d_in[17];
    const float* lnw  = (const float*)d_in[18];
    const float* lnb  = (const float*)d_in[19];

    float* xres = (float*)d_out;                               // B*N*FT*T
    float* spat = xres + (size_t)NB * NN * NFT * NT;           // B*N*N

    float* ws = (float*)d_ws;
    float* P       = ws;                   // 16777216 (reused as h1/h2 later)
    float* h1      = ws;                   // 6291456
    float* h2      = ws + 6291456;         // 6291456
    float* xT      = ws + 16777216;        // 6291456
    float* lhs_pre = xT + 6291456;         // 6144
    float* lhs     = lhs_pre + 6144;       // 196608
    float* rhs     = lhs + 196608;         // 196608
    float* prod    = rhs + 196608;         // 2304
    float* E       = prod + 2304;          // 2304
    float* l2      = E + 2304;             // 196608
    float* r2      = l2 + 196608;          // 196608
    float* sup     = r2 + 196608;          // 1048576
    float* poly2   = sup + 1048576;        // 1048576
    float* wn      = poly2 + 1048576;      // 12288
    float* gsum    = wn + 12288;           // 1

    hipMemsetAsync(lhs_pre, 0, 6144 * sizeof(float), stream);
    hipMemsetAsync(gsum, 0, sizeof(float), stream);

    k_lhspre<<<dim3(16, 32), 384, 0, stream>>>(x, U1, lhs_pre);
    k_rhs<<<2048, 384, 0, stream>>>(x, U3, rhs);
    k_lhs<<<192, 256, 0, stream>>>(lhs_pre, U2, lhs);
    k_prod<<<2304, 64, 0, stream>>>(lhs, rhs, prod);
    k_E<<<16, 192, 0, stream>>>(prod, be, Ve, E);
    k_xTAt<<<dim3(128, 16), 384, 0, stream>>>(x, E, xT);
    k_l2r2<<<dim3(128, 16), 384, 0, stream>>>(xT, W1, W2, W3, l2, r2);
    k_P<<<dim3(4, 1024, 16), 256, 0, stream>>>(l2, r2, bs, P);
    gemm_s<<<dim3(16, 16, 16), 256, 0, stream>>>(Vs, P, spat, NN, NN, NN, NN,
                                                 (long)NN * NN, (long)NN * NN, 1.f, 0);
    k_softmax<<<dim3(16, 16), 256, 0, stream>>>(spat, gsum);
    k_thresh<<<2048, 256, 0, stream>>>(spat, gsum);
    k_sup<<<1024, 256, 0, stream>>>(emb, sup);
    gemm_s<<<dim3(16, 16, 1), 256, 0, stream>>>(sup, sup, poly2, NN, NN, NN, NN, 0, 0, 2.f, 1);
    gemm_h<<<dim3(6, 16, 16), 256, 0, stream>>>(sup, spat, x, h1);
    gemm_h<<<dim3(6, 16, 16), 256, 0, stream>>>(poly2, spat, x, h2);
    k_wnorm<<<64, 192, 0, stream>>>(tcv, tcg, wn);
    k_final<<<dim3(128, 16), 256, 0, stream>>>(x, h1, h2, spat, Theta, wn, tcb,
                                               rcw, rcb, lnw, lnb, xres);
}

// Round 2
// 1032.433 us; speedup vs baseline: 1.9146x; 1.9146x over previous
//
#include <hip/hip_runtime.h>
#include <math.h>

#define NB 16      // B
#define NN 1024    // N
#define NF 32      // F
#define NT 12      // T
#define NFC 64
#define NFT 64

typedef __attribute__((ext_vector_type(8))) short bf16x8;
typedef __attribute__((ext_vector_type(4))) float f32x4;

__device__ inline unsigned short cvt_bf(float f) {
    unsigned int u = __float_as_uint(f);
    u += 0x7fff + ((u >> 16) & 1);
    return (unsigned short)(u >> 16);
}
__device__ inline float bf2f(unsigned short u) {
    return __uint_as_float(((unsigned int)u) << 16);
}
__device__ inline void gll16(const short* g, short* l) {
    __builtin_amdgcn_global_load_lds((const __attribute__((address_space(1))) void*)g,
                                     (__attribute__((address_space(3))) void*)l, 16, 0, 0);
}

// ---------------- temporal attention ----------------

__global__ __launch_bounds__(384) void k_lhspre(const float* __restrict__ x,
                                                const float* __restrict__ U1,
                                                float* __restrict__ lhs_pre)
{
    int b = blockIdx.x, ch = blockIdx.y, tid = threadIdx.x;
    int f = tid / 12, t = tid - f * 12;
    float acc = 0.f;
    int n0 = ch * 32;
    for (int n = n0; n < n0 + 32; n++)
        acc += x[((size_t)(b * NN + n)) * 384 + tid] * U1[n];
    atomicAdd(&lhs_pre[b * 384 + t * 32 + f], acc);
}

__global__ __launch_bounds__(384) void k_rhs(const float* __restrict__ x,
                                             const float* __restrict__ U3,
                                             float* __restrict__ rhs)
{
    __shared__ float sm[8 * 384];
    int tid = threadIdx.x;
    size_t r0 = (size_t)blockIdx.x * 8;
    for (int i = 0; i < 8; i++) sm[i * 384 + tid] = x[(r0 + i) * 384 + tid];
    __syncthreads();
    if (tid < 96) {
        int i = tid / 12, t = tid - i * 12;
        float s = 0.f;
        for (int f = 0; f < 32; f++) s += U3[f] * sm[i * 384 + f * 12 + t];
        rhs[(r0 + i) * 12 + t] = s;
    }
}

__global__ __launch_bounds__(256) void k_lhs(const float* __restrict__ lhs_pre,
                                             const float* __restrict__ U2,
                                             float* __restrict__ lhs)
{
    int bt = blockIdx.x;
    int tid = threadIdx.x;
    __shared__ float lp[32];
    if (tid < 32) lp[tid] = lhs_pre[bt * 32 + tid];
    __syncthreads();
    for (int q = 0; q < 4; q++) {
        int n = q * 256 + tid;
        float a = 0.f;
        for (int f = 0; f < 32; f++) a += lp[f] * U2[f * NN + n];
        lhs[(size_t)bt * NN + n] = a;
    }
}

__global__ __launch_bounds__(64) void k_prod(const float* __restrict__ lhs,
                                             const float* __restrict__ rhs,
                                             float* __restrict__ prod)
{
    int blk = blockIdx.x;
    int b = blk / 144, r = blk - b * 144;
    int s = r / 12, u = r - s * 12;
    int tid = threadIdx.x;
    float p = 0.f;
    for (int n = tid; n < NN; n += 64)
        p += lhs[((size_t)b * 12 + s) * NN + n] * rhs[((size_t)b * NN + n) * 12 + u];
    for (int o = 32; o > 0; o >>= 1) p += __shfl_xor(p, o);
    if (tid == 0) prod[blk] = p;
}

__global__ __launch_bounds__(192) void k_E(const float* __restrict__ prod,
                                           const float* __restrict__ be,
                                           const float* __restrict__ Ve,
                                           float* __restrict__ E)
{
    int b = blockIdx.x, tid = threadIdx.x;
    __shared__ float ssig[144], sE[144], mx[12], sm[12];
    if (tid < 144) ssig[tid] = 1.f / (1.f + expf(-(prod[b * 144 + tid] + be[tid])));
    __syncthreads();
    if (tid < 144) {
        int t = tid / 12, u = tid - t * 12;
        float a = 0.f;
        for (int s2 = 0; s2 < 12; s2++) a += Ve[t * 12 + s2] * ssig[s2 * 12 + u];
        sE[tid] = a;
    }
    __syncthreads();
    if (tid < 12) {
        float m = -1e30f;
        for (int t = 0; t < 12; t++) m = fmaxf(m, sE[t * 12 + tid]);
        float s = 0.f;
        for (int t = 0; t < 12; t++) s += expf(sE[t * 12 + tid] - m);
        mx[tid] = m; sm[tid] = s;
    }
    __syncthreads();
    if (tid < 144) {
        int u = tid % 12;
        E[b * 144 + tid] = expf(sE[tid] - mx[u]) / sm[u];
    }
}

__global__ __launch_bounds__(384) void k_xTAt(const float* __restrict__ x,
                                              const float* __restrict__ E,
                                              float* __restrict__ xT)
{
    __shared__ float xs[8 * 384], Es[144];
    int b = blockIdx.y, tid = threadIdx.x;
    size_t r0 = (size_t)b * NN + (size_t)blockIdx.x * 8;
    if (tid < 144) Es[tid] = E[b * 144 + tid];
    for (int i = 0; i < 8; i++) xs[i * 384 + tid] = x[(r0 + i) * 384 + tid];
    __syncthreads();
    int f = tid / 12, u = tid - f * 12;
    for (int i = 0; i < 8; i++) {
        float a = 0.f;
#pragma unroll
        for (int t = 0; t < 12; t++) a += xs[i * 384 + f * 12 + t] * Es[t * 12 + u];
        xT[(r0 + i) * 384 + f * 12 + u] = a;
    }
}

// ---------------- spatial attention ----------------

__global__ __launch_bounds__(384) void k_l2r2(const float* __restrict__ xT,
                                              const float* __restrict__ W1,
                                              const float* __restrict__ W2,
                                              const float* __restrict__ W3,
                                              float* __restrict__ l2,
                                              float* __restrict__ r2)
{
    __shared__ float xs[8 * 384];
    __shared__ float lp[8][32];
    int b = blockIdx.y, tid = threadIdx.x;
    int n0 = blockIdx.x * 8;
    size_t r0 = (size_t)b * NN + n0;
    for (int i = 0; i < 8; i++) xs[i * 384 + tid] = xT[(r0 + i) * 384 + tid];
    __syncthreads();
    if (tid < 256) {
        int i = tid >> 5, f = tid & 31;
        float a = 0.f;
#pragma unroll
        for (int t = 0; t < 12; t++) a += xs[i * 384 + f * 12 + t] * W1[t];
        lp[i][f] = a;
    }
    __syncthreads();
    if (tid < 96) {
        int i = tid / 12, t = tid - i * 12;
        float a = 0.f, rr = 0.f;
        for (int f = 0; f < 32; f++) {
            a += lp[i][f] * W2[f * 12 + t];
            rr += W3[f] * xs[i * 384 + f * 12 + t];
        }
        l2[(r0 + i) * 12 + t] = a;
        r2[((size_t)b * 12 + t) * NN + n0 + i] = rr;
    }
}

// bs_t[k][m] = bs[m][k]
__global__ __launch_bounds__(256) void k_tbs(const float* __restrict__ bsin,
                                             float* __restrict__ bst)
{
    __shared__ float tl[64][65];
    int m0 = blockIdx.y * 64, k0 = blockIdx.x * 64;
    int tid = threadIdx.x;
    int c = tid & 63, r0 = tid >> 6;
    for (int i = 0; i < 16; i++) {
        int r = r0 + i * 4;
        tl[r][c] = bsin[(size_t)(m0 + r) * NN + k0 + c];
    }
    __syncthreads();
    for (int i = 0; i < 16; i++) {
        int r = r0 + i * 4;
        bst[(size_t)(k0 + r) * NN + m0 + c] = tl[c][r];
    }
}

// P_t[b][k][m] = bf16(sigmoid(sum_t l2[b,m,t]*r2[b,t,k] + bs[m,k]))
__global__ __launch_bounds__(256) void k_P_t(const float* __restrict__ l2,
                                             const float* __restrict__ r2,
                                             const float* __restrict__ bst,
                                             unsigned short* __restrict__ Pt)
{
    int b = blockIdx.y, k = blockIdx.x;
    int tid = threadIdx.x;
    float rv[12];
#pragma unroll
    for (int t = 0; t < 12; t++) rv[t] = r2[((size_t)b * 12 + t) * NN + k];
    for (int q = 0; q < 4; q++) {
        int m = q * 256 + tid;
        const float* lp = &l2[((size_t)b * NN + m) * 12];
        float p = 0.f;
#pragma unroll
        for (int t = 0; t < 12; t++) p += lp[t] * rv[t];
        p += bst[(size_t)k * NN + m];
        float sg = 1.f / (1.f + expf(-p));
        Pt[((size_t)b * NN + k) * NN + m] = cvt_bf(sg);
    }
}

// Vs fp32 -> bf16
__global__ __launch_bounds__(256) void k_cvt(const float* __restrict__ s,
                                             unsigned short* __restrict__ d)
{
    size_t i = ((size_t)blockIdx.x * 256 + threadIdx.x) * 4;
    float4 v = *(const float4*)(s + i);
    unsigned int p0 = (unsigned int)cvt_bf(v.x) | ((unsigned int)cvt_bf(v.y) << 16);
    unsigned int p1 = (unsigned int)cvt_bf(v.z) | ((unsigned int)cvt_bf(v.w) << 16);
    *(unsigned int*)(d + i) = p0;
    *(unsigned int*)(d + i + 2) = p1;
}

// ---------------- MFMA bf16 NT GEMM: C[bz][i][j] = sum_k A[i][k]*B[bz][j][k] ----------------
// A row-major [M][K] bf16 (shared if sA==0), B row-major [N][K] bf16, C fp32 or bf16.
// 128x128 tile, BK=64, 4 waves, global_load_lds width 16 (m97 structure).
template<int OUT_BF16>
__global__ __launch_bounds__(256) void mgemm(const short* __restrict__ A,
                                             const short* __restrict__ B,
                                             void* __restrict__ Cv,
                                             int Kd, int ldA, int ldB, int ldC,
                                             long sA, long sB, long sC)
{
    int bz = blockIdx.z;
    const short* Ab = A + (size_t)bz * sA;
    const short* Bb = B + (size_t)bz * sB;
    int i0 = blockIdx.y * 128, j0 = blockIdx.x * 128;
    __shared__ short sm[16384];            // As [128][64] @0, Bs [128][64] @8192
    int tid = threadIdx.x;
    int ln = tid & 63, wv = tid >> 6;
    int wm = (wv >> 1) * 64, wn = (wv & 1) * 64;
    int fr = ln & 15, fk = ln >> 4;
    f32x4 acc[4][4];
#pragma unroll
    for (int a = 0; a < 4; a++)
#pragma unroll
        for (int b2 = 0; b2 < 4; b2++) acc[a][b2] = (f32x4)(0.f);

    for (int k0 = 0; k0 < Kd; k0 += 64) {
#pragma unroll
        for (int q = 0; q < 4; q++) {      // stage A (16 KB)
            int e = q * 2048 + tid * 8;
            const short* src = Ab + (size_t)(i0 + (e >> 6)) * ldA + k0 + (e & 63);
            gll16(src, sm + e);
        }
#pragma unroll
        for (int q = 0; q < 4; q++) {      // stage B (16 KB)
            int e = q * 2048 + tid * 8;
            const short* src = Bb + (size_t)(j0 + (e >> 6)) * ldB + k0 + (e & 63);
            gll16(src, sm + 8192 + e);
        }
        __syncthreads();
#pragma unroll
        for (int ks = 0; ks < 2; ks++) {
            bf16x8 av[4], bv[4];
#pragma unroll
            for (int mi = 0; mi < 4; mi++)
                av[mi] = *(const bf16x8*)(sm + (wm + mi * 16 + fr) * 64 + ks * 32 + fk * 8);
#pragma unroll
            for (int nj = 0; nj < 4; nj++)
                bv[nj] = *(const bf16x8*)(sm + 8192 + (wn + nj * 16 + fr) * 64 + ks * 32 + fk * 8);
#pragma unroll
            for (int mi = 0; mi < 4; mi++)
#pragma unroll
                for (int nj = 0; nj < 4; nj++)
                    acc[mi][nj] = __builtin_amdgcn_mfma_f32_16x16x32_bf16(av[mi], bv[nj], acc[mi][nj], 0, 0, 0);
        }
        __syncthreads();
    }
#pragma unroll
    for (int mi = 0; mi < 4; mi++)
#pragma unroll
        for (int nj = 0; nj < 4; nj++) {
            int row = i0 + wm + mi * 16 + fk * 4;
            int col = j0 + wn + nj * 16 + fr;
            if constexpr (OUT_BF16) {
                unsigned short* Cb = (unsigned short*)Cv + (size_t)bz * sC;
#pragma unroll
                for (int r = 0; r < 4; r++)
                    Cb[(size_t)(row + r) * ldC + col] = cvt_bf(acc[mi][nj][r]);
            } else {
                float* Cb = (float*)Cv + (size_t)bz * sC;
#pragma unroll
                for (int r = 0; r < 4; r++)
                    Cb[(size_t)(row + r) * ldC + col] = acc[mi][nj][r];
            }
        }
}

// ---------------- fp32 GEMM (kept for poly2): C = alpha*A@B (-I opt) ----------------
__global__ __launch_bounds__(256) void gemm_s(const float* __restrict__ A,
                                              const float* __restrict__ Bm,
                                              float* __restrict__ C,
                                              int Kd, int ldA, int ldB, int ldC,
                                              long sB, long sC, float alpha, int subI)
{
    int bz = blockIdx.z;
    const float* Bb = Bm + (size_t)bz * sB;
    float* Cb = C + (size_t)bz * sC;
    int i0 = blockIdx.y * 64, j0 = blockIdx.x * 64;
    __shared__ float As[16][64];
    __shared__ float Bs[16][64];
    int tid = threadIdx.x;
    int tx = tid & 15, ty = tid >> 4;
    int ar = tid >> 2, ac = (tid & 3) << 2;
    int br = tid >> 4, bc = (tid & 15) << 2;
    float acc[4][4];
#pragma unroll
    for (int ii = 0; ii < 4; ii++)
#pragma unroll
        for (int jj = 0; jj < 4; jj++) acc[ii][jj] = 0.f;
    for (int k0 = 0; k0 < Kd; k0 += 16) {
        float4 av = *(const float4*)(A + (size_t)(i0 + ar) * ldA + k0 + ac);
        float4 bv = *(const float4*)(Bb + (size_t)(k0 + br) * ldB + j0 + bc);
        As[ac + 0][ar] = av.x; As[ac + 1][ar] = av.y;
        As[ac + 2][ar] = av.z; As[ac + 3][ar] = av.w;
        *(float4*)(&Bs[br][bc]) = bv;
        __syncthreads();
#pragma unroll
        for (int kk = 0; kk < 16; kk++) {
            float a[4], bf[4];
#pragma unroll
            for (int ii = 0; ii < 4; ii++) a[ii] = As[kk][ii * 16 + ty];
#pragma unroll
            for (int jj = 0; jj < 4; jj++) bf[jj] = Bs[kk][jj * 16 + tx];
#pragma unroll
            for (int ii = 0; ii < 4; ii++)
#pragma unroll
                for (int jj = 0; jj < 4; jj++) acc[ii][jj] += a[ii] * bf[jj];
        }
        __syncthreads();
    }
#pragma unroll
    for (int ii = 0; ii < 4; ii++)
#pragma unroll
        for (int jj = 0; jj < 4; jj++) {
            int gi = i0 + ii * 16 + ty, gj = j0 + jj * 16 + tx;
            float v = alpha * acc[ii][jj];
            if (subI && gi == gj) v -= 1.f;
            Cb[(size_t)gi * ldC + gj] = v;
        }
}

// ---------------- softmax over n (axis=1) in place + global sum ----------------
__global__ __launch_bounds__(256) void k_softmax(float* __restrict__ S, float* __restrict__ gsum)
{
    int b = blockIdx.y;
    int k0 = blockIdx.x * 64;
    int tid = threadIdx.x;
    int kx = tid & 63, ny = tid >> 6;
    float* Sb = S + (size_t)b * NN * NN;
    __shared__ float red[4][64];
    __shared__ float mcol[64], scol[64];
    float vmax = -1e30f;
    for (int n = ny; n < NN; n += 4) vmax = fmaxf(vmax, Sb[(size_t)n * NN + k0 + kx]);
    red[ny][kx] = vmax;
    __syncthreads();
    if (ny == 0) mcol[kx] = fmaxf(fmaxf(red[0][kx], red[1][kx]), fmaxf(red[2][kx], red[3][kx]));
    __syncthreads();
    float mx = mcol[kx];
    float s = 0.f;
    for (int n = ny; n < NN; n += 4) {
        size_t i = (size_t)n * NN + k0 + kx;
        float e = expf(Sb[i] - mx);
        Sb[i] = e;
        s += e;
    }
    red[ny][kx] = s;
    __syncthreads();
    if (ny == 0) scol[kx] = red[0][kx] + red[1][kx] + red[2][kx] + red[3][kx];
    __syncthreads();
    float inv = 1.f / scol[kx];
    float part = 0.f;
    for (int n = ny; n < NN; n += 4) {
        size_t i = (size_t)n * NN + k0 + kx;
        float e = Sb[i] * inv;
        Sb[i] = e;
        part += e;
    }
    for (int o = 32; o > 0; o >>= 1) part += __shfl_xor(part, o);
    __shared__ float wsum[4];
    if ((tid & 63) == 0) wsum[tid >> 6] = part;
    __syncthreads();
    if (tid == 0) atomicAdd(gsum, wsum[0] + wsum[1] + wsum[2] + wsum[3]);
}

__global__ void k_thresh(float* __restrict__ S, const float* __restrict__ gsum)
{
    float thr = (gsum[0] * (1.f / ((float)NB * NN * NN))) / 0.6f;
    size_t i = (size_t)blockIdx.x * blockDim.x + threadIdx.x;
    size_t stride = (size_t)gridDim.x * blockDim.x;
    size_t tot = (size_t)NB * NN * NN;
    for (; i < tot; i += stride) {
        float v = S[i];
        S[i] = (v < thr) ? 0.f : v;
    }
}

// ---------------- support graph ----------------
__global__ __launch_bounds__(256) void k_sup(const float* __restrict__ emb, float* __restrict__ sup)
{
    int n = blockIdx.x, tid = threadIdx.x;
    __shared__ float en[16];
    if (tid < 16) en[tid] = emb[n * 16 + tid];
    __syncthreads();
    float v[4];
#pragma unroll
    for (int q = 0; q < 4; q++) {
        int m = q * 256 + tid;
        float d = 0.f;
#pragma unroll
        for (int dd = 0; dd < 16; dd++) d += en[dd] * emb[m * 16 + dd];
        v[q] = fmaxf(d, 0.f);
    }
    float mx = fmaxf(fmaxf(v[0], v[1]), fmaxf(v[2], v[3]));
    for (int o = 32; o > 0; o >>= 1) mx = fmaxf(mx, __shfl_xor(mx, o));
    __shared__ float red[4];
    if ((tid & 63) == 0) red[tid >> 6] = mx;
    __syncthreads();
    mx = fmaxf(fmaxf(red[0], red[1]), fmaxf(red[2], red[3]));
    float e[4];
    float s = 0.f;
#pragma unroll
    for (int q = 0; q < 4; q++) { e[q] = expf(v[q] - mx); s += e[q]; }
    for (int o = 32; o > 0; o >>= 1) s += __shfl_xor(s, o);
    __shared__ float red2[4];
    if ((tid & 63) == 0) red2[tid >> 6] = s;
    __syncthreads();
    s = red2[0] + red2[1] + red2[2] + red2[3];
    float inv = 1.f / s;
#pragma unroll
    for (int q = 0; q < 4; q++) sup[(size_t)n * NN + q * 256 + tid] = e[q] * inv;
}

// A_t[b][m][n] = bf16(G[n][m] * spat[b][n][m])
__global__ __launch_bounds__(256) void k_prep(const float* __restrict__ G,
                                              const float* __restrict__ spat,
                                              unsigned short* __restrict__ At)
{
    __shared__ float tl[64][65];
    int b = blockIdx.z;
    int n0 = blockIdx.y * 64, m0 = blockIdx.x * 64;
    int tid = threadIdx.x;
    int c = tid & 63, r0 = tid >> 6;
    const float* sp = spat + (size_t)b * NN * NN;
    for (int i = 0; i < 16; i++) {
        int r = r0 + i * 4;
        tl[r][c] = G[(size_t)(n0 + r) * NN + m0 + c] * sp[(size_t)(n0 + r) * NN + m0 + c];
    }
    __syncthreads();
    int c2 = tid & 31, r4 = tid >> 5;
    unsigned short* ob = At + ((size_t)b * NN + m0) * NN + n0;
    for (int i = 0; i < 8; i++) {
        int rr = r4 + i * 8;
        unsigned int v0 = cvt_bf(tl[2 * c2][rr]);
        unsigned int v1 = cvt_bf(tl[2 * c2 + 1][rr]);
        *(unsigned int*)(ob + (size_t)rr * NN + 2 * c2) = v0 | (v1 << 16);
    }
}

// Xt[b][j][n] = bf16(x[b][n][j])
__global__ __launch_bounds__(256) void k_xt(const float* __restrict__ x,
                                            unsigned short* __restrict__ Xt)
{
    __shared__ float tl[64][65];
    int b = blockIdx.z;
    int n0 = blockIdx.y * 64, j0 = blockIdx.x * 64;
    int tid = threadIdx.x;
    int c = tid & 63, r0 = tid >> 6;
    for (int i = 0; i < 16; i++) {
        int r = r0 + i * 4;
        tl[r][c] = x[((size_t)b * NN + n0 + r) * 384 + j0 + c];
    }
    __syncthreads();
    int c2 = tid & 31, r4 = tid >> 5;
    unsigned short* ob = Xt + ((size_t)b * 384 + j0) * NN + n0;
    for (int i = 0; i < 8; i++) {
        int jj = r4 + i * 8;
        unsigned int v0 = cvt_bf(tl[2 * c2][jj]);
        unsigned int v1 = cvt_bf(tl[2 * c2 + 1][jj]);
        *(unsigned int*)(ob + (size_t)jj * NN + 2 * c2) = v0 | (v1 << 16);
    }
}

// ---------------- weight norm ----------------
__global__ __launch_bounds__(192) void k_wnorm(const float* __restrict__ tcv,
                                               const float* __restrict__ tcg,
                                               float* __restrict__ wn)
{
    int o = blockIdx.x, tid = threadIdx.x;
    float t = tcv[o * 192 + tid];
    float p = t * t;
    for (int off = 32; off > 0; off >>= 1) p += __shfl_xor(p, off);
    __shared__ float wsr[3];
    if ((tid & 63) == 0) wsr[tid >> 6] = p;
    __syncthreads();
    float sum = wsr[0] + wsr[1] + wsr[2];
    wn[o * 192 + tid] = t * (tcg[o] / sqrtf(sum));
}

// ---------------- fused tail ----------------
__global__ __launch_bounds__(256) void k_final(const float* __restrict__ x,
                                               const unsigned short* __restrict__ h1,
                                               const unsigned short* __restrict__ h2,
                                               const float* __restrict__ spat,
                                               const float* __restrict__ Theta,
                                               const float* __restrict__ wn,
                                               const float* __restrict__ tcb,
                                               const float* __restrict__ rcw,
                                               const float* __restrict__ rcb,
                                               const float* __restrict__ lnw,
                                               const float* __restrict__ lnb,
                                               float* __restrict__ out)
{
    int b = blockIdx.y;
    int tid = threadIdx.x;
    __shared__ float wns[64 * 195];
    __shared__ float rcs[64 * 33];
    __shared__ float xs[384], h1s[384], h2s[384];
    __shared__ float gcnS[768];
    __shared__ float yS[768];
    __shared__ float mu[12], rstd[12];
    for (int i = tid; i < 12288; i += 256) {
        int o = i / 192, cd = i - o * 192;
        wns[o * 195 + cd] = wn[i];
    }
    for (int i = tid; i < 2048; i += 256) {
        int o = i >> 5, f = i & 31;
        rcs[o * 33 + f] = rcw[i];
    }
    for (int mi = 0; mi < 8; mi++) {
        int m = blockIdx.x * 8 + mi;
        size_t row = ((size_t)b * NN + m) * 384;
        for (int i = tid; i < 384; i += 256) {
            xs[i] = x[row + i];
            h1s[i] = bf2f(h1[row + i]);
            h2s[i] = bf2f(h2[row + i]);
        }
        __syncthreads();
        float sd = spat[(size_t)b * NN * NN + (size_t)m * NN + m];
        for (int idx = tid; idx < 768; idx += 256) {
            int t = idx >> 6, o = idx & 63;
            float acc = 0.f;
#pragma unroll 8
            for (int f = 0; f < 32; f++) {
                acc += (sd * xs[f * 12 + t]) * Theta[f * 64 + o]
                     + h1s[f * 12 + t] * Theta[2048 + f * 64 + o]
                     + h2s[f * 12 + t] * Theta[4096 + f * 64 + o];
            }
            gcnS[idx] = fmaxf(acc, 0.f);
        }
        __syncthreads();
        for (int idx = tid; idx < 768; idx += 256) {
            int t = idx >> 6, o = idx & 63;
            float v = tcb[o];
            for (int dt = 0; dt < 3; dt++) {
                int tt = t + dt - 1;
                if (tt < 0 || tt >= 12) continue;
                const float* g = &gcnS[tt * 64];
                const float* w = &wns[o * 195 + dt];
                float a = 0.f;
#pragma unroll 16
                for (int c = 0; c < 64; c++) a += w[c * 3] * g[c];
                v += a;
            }
            float rr = rcb[o];
#pragma unroll 8
            for (int f = 0; f < 32; f++) rr += rcs[o * 33 + f] * xs[f * 12 + t];
            yS[idx] = v + rr;
        }
        __syncthreads();
        if (tid < 12) {
            float s = 0.f, s2 = 0.f;
            for (int o = 0; o < 64; o++) {
                float v = yS[tid * 64 + o];
                s += v; s2 += v * v;
            }
            float mm = s * (1.f / 64.f);
            float var = s2 * (1.f / 64.f) - mm * mm;
            mu[tid] = mm;
            rstd[tid] = rsqrtf(var + 1e-5f);
        }
        __syncthreads();
        size_t obase = ((size_t)b * NN + m) * 768;
        for (int idx = tid; idx < 768; idx += 256) {
            int o = idx / 12, t = idx - o * 12;
            out[obase + idx] = (yS[t * 64 + o] - mu[t]) * rstd[t] * lnw[o] + lnb[o];
        }
        __syncthreads();
    }
}

extern "C" void kernel_launch(void* const* d_in, const int* in_sizes, int n_in,
                              void* d_out, int out_size, void* d_ws, size_t ws_size,
                              hipStream_t stream)
{
    const float* x    = (const float*)d_in[0];
    const float* emb  = (const float*)d_in[1];
    const float* W1   = (const float*)d_in[2];
    const float* W2   = (const float*)d_in[3];
    const float* W3   = (const float*)d_in[4];
    const float* bs   = (const float*)d_in[5];
    const float* Vs   = (const float*)d_in[6];
    const float* U1   = (const float*)d_in[7];
    const float* U2   = (const float*)d_in[8];
    const float* U3   = (const float*)d_in[9];
    const float* be   = (const float*)d_in[10];
    const float* Ve   = (const float*)d_in[11];
    const float* Theta= (const float*)d_in[12];
    const float* tcv  = (const float*)d_in[13];
    const float* tcg  = (const float*)d_in[14];
    const float* tcb  = (const float*)d_in[15];
    const float* rcw  = (const float*)d_in[16];
    const float* rcb  = (const float*)d_in[17];
    const float* lnw  = (const float*)d_in[18];
    const float* lnb  = (const float*)d_in[19];

    float* xres = (float*)d_out;                       // B*N*FT*T fp32
    float* spat = xres + (size_t)NB * NN * NFT * NT;   // B*N*N fp32

    char* base = (char*)d_ws;
    // R1: P_t -> A1t -> A2t (bf16, 33.5 MB)
    unsigned short* Pt  = (unsigned short*)(base + 0);
    unsigned short* At  = (unsigned short*)(base + 0);
    // R2: xT fp32 (25.2 MB) -> { Xt bf16 (12.58 MB) | h1 bf16 (12.58 MB) }
    float*          xT  = (float*)(base + 33554432);
    unsigned short* Xt  = (unsigned short*)(base + 33554432);
    unsigned short* h1  = (unsigned short*)(base + 46137344);
    unsigned short* h2  = (unsigned short*)(base + 58720256);
    unsigned short* Vsb = (unsigned short*)(base + 71303168);
    float* bst     = (float*)(base + 73400320);
    float* sup     = (float*)(base + 77594624);
    float* poly2   = (float*)(base + 81788928);
    float* lhs_pre = (float*)(base + 85983232);
    float* lhs     = (float*)(base + 86007808);
    float* rhs     = (float*)(base + 86794240);
    float* prod    = (float*)(base + 87580672);
    float* E       = (float*)(base + 87589888);
    float* l2      = (float*)(base + 87599104);
    float* r2      = (float*)(base + 88385536);
    float* wn      = (float*)(base + 89171968);
    float* gsum    = (float*)(base + 89221120);

    hipMemsetAsync(lhs_pre, 0, 6144 * sizeof(float), stream);
    hipMemsetAsync(gsum, 0, sizeof(float), stream);

    // temporal attention
    k_lhspre<<<dim3(16, 32), 384, 0, stream>>>(x, U1, lhs_pre);
    k_rhs<<<2048, 384, 0, stream>>>(x, U3, rhs);
    k_lhs<<<192, 256, 0, stream>>>(lhs_pre, U2, lhs);
    k_prod<<<2304, 64, 0, stream>>>(lhs, rhs, prod);
    k_E<<<16, 192, 0, stream>>>(prod, be, Ve, E);
    k_xTAt<<<dim3(128, 16), 384, 0, stream>>>(x, E, xT);
    // spatial attention
    k_l2r2<<<dim3(128, 16), 384, 0, stream>>>(xT, W1, W2, W3, l2, r2);
    k_tbs<<<dim3(16, 16), 256, 0, stream>>>(bs, bst);
    k_P_t<<<dim3(1024, 16), 256, 0, stream>>>(l2, r2, bst, Pt);
    k_cvt<<<1024, 256, 0, stream>>>(Vs, Vsb);
    mgemm<0><<<dim3(8, 8, 16), 256, 0, stream>>>((const short*)Vsb, (const short*)Pt,
        (void*)spat, NN, NN, NN, NN, 0L, (long)NN * NN, (long)NN * NN);
    k_softmax<<<dim3(16, 16), 256, 0, stream>>>(spat, gsum);
    k_thresh<<<2048, 256, 0, stream>>>(spat, gsum);
    // graph conv
    k_sup<<<1024, 256, 0, stream>>>(emb, sup);
    gemm_s<<<dim3(16, 16, 1), 256, 0, stream>>>(sup, sup, poly2, NN, NN, NN, NN, 0, 0, 2.f, 1);
    k_xt<<<dim3(6, 16, 16), 256, 0, stream>>>(x, Xt);
    k_prep<<<dim3(16, 16, 16), 256, 0, stream>>>(sup, spat, At);
    mgemm<1><<<dim3(3, 8, 16), 256, 0, stream>>>((const short*)At, (const short*)Xt,
        (void*)h1, NN, NN, NN, 384, (long)NN * NN, 384L * NN, (long)NN * 384);
    k_prep<<<dim3(16, 16, 16), 256, 0, stream>>>(poly2, spat, At);
    mgemm<1><<<dim3(3, 8, 16), 256, 0, stream>>>((const short*)At, (const short*)Xt,
        (void*)h2, NN, NN, NN, 384, (long)NN * NN, 384L * NN, (long)NN * 384);
    // tail
    k_wnorm<<<64, 192, 0, stream>>>(tcv, tcg, wn);
    k_final<<<dim3(128, 16), 256, 0, stream>>>(x, h1, h2, spat, Theta, wn, tcb,
                                               rcw, rcb, lnw, lnb, xres);
}

// Round 3
// 607.080 us; speedup vs baseline: 3.2560x; 1.7007x over previous
//
#include <hip/hip_runtime.h>
#include <math.h>

#define NB 16      // B
#define NN 1024    // N
#define NF 32      // F
#define NT 12      // T
#define NFC 64
#define NFT 64

typedef __attribute__((ext_vector_type(8))) short bf16x8;
typedef __attribute__((ext_vector_type(4))) float f32x4;

__device__ inline unsigned short cvt_bf(float f) {
    unsigned int u = __float_as_uint(f);
    u += 0x7fff + ((u >> 16) & 1);
    return (unsigned short)(u >> 16);
}
__device__ inline float bf2f(unsigned short u) {
    return __uint_as_float(((unsigned int)u) << 16);
}
__device__ inline void gll16(const short* g, short* l) {
    __builtin_amdgcn_global_load_lds((const __attribute__((address_space(1))) void*)g,
                                     (__attribute__((address_space(3))) void*)l, 16, 0, 0);
}

// ---------------- temporal attention ----------------

__global__ __launch_bounds__(384) void k_lhspre(const float* __restrict__ x,
                                                const float* __restrict__ U1,
                                                float* __restrict__ lhs_pre)
{
    int b = blockIdx.x, ch = blockIdx.y, tid = threadIdx.x;
    int f = tid / 12, t = tid - f * 12;
    float acc = 0.f;
    int n0 = ch * 32;
    for (int n = n0; n < n0 + 32; n++)
        acc += x[((size_t)(b * NN + n)) * 384 + tid] * U1[n];
    atomicAdd(&lhs_pre[b * 384 + t * 32 + f], acc);
}

__global__ __launch_bounds__(384) void k_rhs(const float* __restrict__ x,
                                             const float* __restrict__ U3,
                                             float* __restrict__ rhs)
{
    __shared__ float sm[8 * 384];
    int tid = threadIdx.x;
    size_t r0 = (size_t)blockIdx.x * 8;
    for (int i = 0; i < 8; i++) sm[i * 384 + tid] = x[(r0 + i) * 384 + tid];
    __syncthreads();
    if (tid < 96) {
        int i = tid / 12, t = tid - i * 12;
        float s = 0.f;
        for (int f = 0; f < 32; f++) s += U3[f] * sm[i * 384 + f * 12 + t];
        rhs[(r0 + i) * 12 + t] = s;
    }
}

__global__ __launch_bounds__(256) void k_lhs(const float* __restrict__ lhs_pre,
                                             const float* __restrict__ U2,
                                             float* __restrict__ lhs)
{
    int bt = blockIdx.x;
    int tid = threadIdx.x;
    __shared__ float lp[32];
    if (tid < 32) lp[tid] = lhs_pre[bt * 32 + tid];
    __syncthreads();
    for (int q = 0; q < 4; q++) {
        int n = q * 256 + tid;
        float a = 0.f;
        for (int f = 0; f < 32; f++) a += lp[f] * U2[f * NN + n];
        lhs[(size_t)bt * NN + n] = a;
    }
}

__global__ __launch_bounds__(64) void k_prod(const float* __restrict__ lhs,
                                             const float* __restrict__ rhs,
                                             float* __restrict__ prod)
{
    int blk = blockIdx.x;
    int b = blk / 144, r = blk - b * 144;
    int s = r / 12, u = r - s * 12;
    int tid = threadIdx.x;
    float p = 0.f;
    for (int n = tid; n < NN; n += 64)
        p += lhs[((size_t)b * 12 + s) * NN + n] * rhs[((size_t)b * NN + n) * 12 + u];
    for (int o = 32; o > 0; o >>= 1) p += __shfl_xor(p, o);
    if (tid == 0) prod[blk] = p;
}

__global__ __launch_bounds__(192) void k_E(const float* __restrict__ prod,
                                           const float* __restrict__ be,
                                           const float* __restrict__ Ve,
                                           float* __restrict__ E)
{
    int b = blockIdx.x, tid = threadIdx.x;
    __shared__ float ssig[144], sE[144], mx[12], sm[12];
    if (tid < 144) ssig[tid] = 1.f / (1.f + expf(-(prod[b * 144 + tid] + be[tid])));
    __syncthreads();
    if (tid < 144) {
        int t = tid / 12, u = tid - t * 12;
        float a = 0.f;
        for (int s2 = 0; s2 < 12; s2++) a += Ve[t * 12 + s2] * ssig[s2 * 12 + u];
        sE[tid] = a;
    }
    __syncthreads();
    if (tid < 12) {
        float m = -1e30f;
        for (int t = 0; t < 12; t++) m = fmaxf(m, sE[t * 12 + tid]);
        float s = 0.f;
        for (int t = 0; t < 12; t++) s += expf(sE[t * 12 + tid] - m);
        mx[tid] = m; sm[tid] = s;
    }
    __syncthreads();
    if (tid < 144) {
        int u = tid % 12;
        E[b * 144 + tid] = expf(sE[tid] - mx[u]) / sm[u];
    }
}

__global__ __launch_bounds__(384) void k_xTAt(const float* __restrict__ x,
                                              const float* __restrict__ E,
                                              float* __restrict__ xT)
{
    __shared__ float xs[8 * 384], Es[144];
    int b = blockIdx.y, tid = threadIdx.x;
    size_t r0 = (size_t)b * NN + (size_t)blockIdx.x * 8;
    if (tid < 144) Es[tid] = E[b * 144 + tid];
    for (int i = 0; i < 8; i++) xs[i * 384 + tid] = x[(r0 + i) * 384 + tid];
    __syncthreads();
    int f = tid / 12, u = tid - f * 12;
    for (int i = 0; i < 8; i++) {
        float a = 0.f;
#pragma unroll
        for (int t = 0; t < 12; t++) a += xs[i * 384 + f * 12 + t] * Es[t * 12 + u];
        xT[(r0 + i) * 384 + f * 12 + u] = a;
    }
}

// ---------------- spatial attention ----------------

__global__ __launch_bounds__(384) void k_l2r2(const float* __restrict__ xT,
                                              const float* __restrict__ W1,
                                              const float* __restrict__ W2,
                                              const float* __restrict__ W3,
                                              float* __restrict__ l2,
                                              float* __restrict__ r2)
{
    __shared__ float xs[8 * 384];
    __shared__ float lp[8][32];
    int b = blockIdx.y, tid = threadIdx.x;
    int n0 = blockIdx.x * 8;
    size_t r0 = (size_t)b * NN + n0;
    for (int i = 0; i < 8; i++) xs[i * 384 + tid] = xT[(r0 + i) * 384 + tid];
    __syncthreads();
    if (tid < 256) {
        int i = tid >> 5, f = tid & 31;
        float a = 0.f;
#pragma unroll
        for (int t = 0; t < 12; t++) a += xs[i * 384 + f * 12 + t] * W1[t];
        lp[i][f] = a;
    }
    __syncthreads();
    if (tid < 96) {
        int i = tid / 12, t = tid - i * 12;
        float a = 0.f, rr = 0.f;
        for (int f = 0; f < 32; f++) {
            a += lp[i][f] * W2[f * 12 + t];
            rr += W3[f] * xs[i * 384 + f * 12 + t];
        }
        l2[(r0 + i) * 12 + t] = a;
        r2[((size_t)b * 12 + t) * NN + n0 + i] = rr;
    }
}

// bs_t[k][m] = bs[m][k]
__global__ __launch_bounds__(256) void k_tbs(const float* __restrict__ bsin,
                                             float* __restrict__ bst)
{
    __shared__ float tl[64][65];
    int m0 = blockIdx.y * 64, k0 = blockIdx.x * 64;
    int tid = threadIdx.x;
    int c = tid & 63, r0 = tid >> 6;
    for (int i = 0; i < 16; i++) {
        int r = r0 + i * 4;
        tl[r][c] = bsin[(size_t)(m0 + r) * NN + k0 + c];
    }
    __syncthreads();
    for (int i = 0; i < 16; i++) {
        int r = r0 + i * 4;
        bst[(size_t)(k0 + r) * NN + m0 + c] = tl[c][r];
    }
}

// P_t[b][k][m] = bf16(sigmoid(sum_t l2[b,m,t]*r2[b,t,k] + bs[m,k]))
__global__ __launch_bounds__(256) void k_P_t(const float* __restrict__ l2,
                                             const float* __restrict__ r2,
                                             const float* __restrict__ bst,
                                             unsigned short* __restrict__ Pt)
{
    int b = blockIdx.y, k = blockIdx.x;
    int tid = threadIdx.x;
    float rv[12];
#pragma unroll
    for (int t = 0; t < 12; t++) rv[t] = r2[((size_t)b * 12 + t) * NN + k];
    for (int q = 0; q < 4; q++) {
        int m = q * 256 + tid;
        const float* lp = &l2[((size_t)b * NN + m) * 12];
        float p = 0.f;
#pragma unroll
        for (int t = 0; t < 12; t++) p += lp[t] * rv[t];
        p += bst[(size_t)k * NN + m];
        float sg = 1.f / (1.f + expf(-p));
        Pt[((size_t)b * NN + k) * NN + m] = cvt_bf(sg);
    }
}

// Vs fp32 -> bf16
__global__ __launch_bounds__(256) void k_cvt(const float* __restrict__ s,
                                             unsigned short* __restrict__ d)
{
    size_t i = ((size_t)blockIdx.x * 256 + threadIdx.x) * 4;
    float4 v = *(const float4*)(s + i);
    unsigned int p0 = (unsigned int)cvt_bf(v.x) | ((unsigned int)cvt_bf(v.y) << 16);
    unsigned int p1 = (unsigned int)cvt_bf(v.z) | ((unsigned int)cvt_bf(v.w) << 16);
    *(unsigned int*)(d + i) = p0;
    *(unsigned int*)(d + i + 2) = p1;
}

// bf16 transpose 1024x1024
__global__ __launch_bounds__(256) void k_tb16(const unsigned short* __restrict__ s,
                                              unsigned short* __restrict__ d)
{
    __shared__ unsigned short tl[64][65];
    int r0 = blockIdx.y * 64, c0 = blockIdx.x * 64;
    int tid = threadIdx.x;
    int c = tid & 63, rr = tid >> 6;
    for (int i = 0; i < 16; i++)
        tl[rr + i * 4][c] = s[(size_t)(r0 + rr + i * 4) * NN + c0 + c];
    __syncthreads();
    for (int i = 0; i < 16; i++)
        d[(size_t)(c0 + rr + i * 4) * NN + r0 + c] = tl[c][rr + i * 4];
}

// ---------------- MFMA bf16 NT GEMM: C[bz][i][j] = alpha*sum_k A[i][k]*B[bz][j][k] (-I opt) --------
template<int OUT_BF16>
__global__ __launch_bounds__(256) void mgemm(const short* __restrict__ A,
                                             const short* __restrict__ B,
                                             void* __restrict__ Cv,
                                             int Kd, int ldA, int ldB, int ldC,
                                             long sA, long sB, long sC,
                                             float alpha, int subI)
{
    int bz = blockIdx.z;
    const short* Ab = A + (size_t)bz * sA;
    const short* Bb = B + (size_t)bz * sB;
    int i0 = blockIdx.y * 128, j0 = blockIdx.x * 128;
    __shared__ short sm[16384];            // As [128][64] @0, Bs [128][64] @8192
    int tid = threadIdx.x;
    int ln = tid & 63, wv = tid >> 6;
    int wm = (wv >> 1) * 64, wn = (wv & 1) * 64;
    int fr = ln & 15, fk = ln >> 4;
    f32x4 acc[4][4];
#pragma unroll
    for (int a = 0; a < 4; a++)
#pragma unroll
        for (int b2 = 0; b2 < 4; b2++) acc[a][b2] = (f32x4)(0.f);

    for (int k0 = 0; k0 < Kd; k0 += 64) {
#pragma unroll
        for (int q = 0; q < 4; q++) {
            int e = q * 2048 + tid * 8;
            const short* src = Ab + (size_t)(i0 + (e >> 6)) * ldA + k0 + (e & 63);
            gll16(src, sm + e);
        }
#pragma unroll
        for (int q = 0; q < 4; q++) {
            int e = q * 2048 + tid * 8;
            const short* src = Bb + (size_t)(j0 + (e >> 6)) * ldB + k0 + (e & 63);
            gll16(src, sm + 8192 + e);
        }
        __syncthreads();
#pragma unroll
        for (int ks = 0; ks < 2; ks++) {
            bf16x8 av[4], bv[4];
#pragma unroll
            for (int mi = 0; mi < 4; mi++)
                av[mi] = *(const bf16x8*)(sm + (wm + mi * 16 + fr) * 64 + ks * 32 + fk * 8);
#pragma unroll
            for (int nj = 0; nj < 4; nj++)
                bv[nj] = *(const bf16x8*)(sm + 8192 + (wn + nj * 16 + fr) * 64 + ks * 32 + fk * 8);
#pragma unroll
            for (int mi = 0; mi < 4; mi++)
#pragma unroll
                for (int nj = 0; nj < 4; nj++)
                    acc[mi][nj] = __builtin_amdgcn_mfma_f32_16x16x32_bf16(av[mi], bv[nj], acc[mi][nj], 0, 0, 0);
        }
        __syncthreads();
    }
#pragma unroll
    for (int mi = 0; mi < 4; mi++)
#pragma unroll
        for (int nj = 0; nj < 4; nj++) {
            int row = i0 + wm + mi * 16 + fk * 4;
            int col = j0 + wn + nj * 16 + fr;
            if constexpr (OUT_BF16) {
                unsigned short* Cb = (unsigned short*)Cv + (size_t)bz * sC;
#pragma unroll
                for (int r = 0; r < 4; r++)
                    Cb[(size_t)(row + r) * ldC + col] = cvt_bf(alpha * acc[mi][nj][r]);
            } else {
                float* Cb = (float*)Cv + (size_t)bz * sC;
#pragma unroll
                for (int r = 0; r < 4; r++) {
                    float v = alpha * acc[mi][nj][r];
                    if (subI && (row + r) == col) v -= 1.f;
                    Cb[(size_t)(row + r) * ldC + col] = v;
                }
            }
        }
}

// ---------------- softmax over n (axis=1) in place + global sum ----------------
__global__ __launch_bounds__(256) void k_softmax(float* __restrict__ S, float* __restrict__ gsum)
{
    int b = blockIdx.y;
    int k0 = blockIdx.x * 64;
    int tid = threadIdx.x;
    int kx = tid & 63, ny = tid >> 6;
    float* Sb = S + (size_t)b * NN * NN;
    __shared__ float red[4][64];
    __shared__ float mcol[64], scol[64];
    float vmax = -1e30f;
    for (int n = ny; n < NN; n += 4) vmax = fmaxf(vmax, Sb[(size_t)n * NN + k0 + kx]);
    red[ny][kx] = vmax;
    __syncthreads();
    if (ny == 0) mcol[kx] = fmaxf(fmaxf(red[0][kx], red[1][kx]), fmaxf(red[2][kx], red[3][kx]));
    __syncthreads();
    float mx = mcol[kx];
    float s = 0.f;
    for (int n = ny; n < NN; n += 4) {
        size_t i = (size_t)n * NN + k0 + kx;
        float e = expf(Sb[i] - mx);
        Sb[i] = e;
        s += e;
    }
    red[ny][kx] = s;
    __syncthreads();
    if (ny == 0) scol[kx] = red[0][kx] + red[1][kx] + red[2][kx] + red[3][kx];
    __syncthreads();
    float inv = 1.f / scol[kx];
    float part = 0.f;
    for (int n = ny; n < NN; n += 4) {
        size_t i = (size_t)n * NN + k0 + kx;
        float e = Sb[i] * inv;
        Sb[i] = e;
        part += e;
    }
    for (int o = 32; o > 0; o >>= 1) part += __shfl_xor(part, o);
    __shared__ float wsum[4];
    if ((tid & 63) == 0) wsum[tid >> 6] = part;
    __syncthreads();
    if (tid == 0) atomicAdd(gsum, wsum[0] + wsum[1] + wsum[2] + wsum[3]);
}

__global__ void k_thresh(float* __restrict__ S, const float* __restrict__ gsum)
{
    float thr = (gsum[0] * (1.f / ((float)NB * NN * NN))) / 0.6f;
    size_t i = (size_t)blockIdx.x * blockDim.x + threadIdx.x;
    size_t stride = (size_t)gridDim.x * blockDim.x;
    size_t tot = (size_t)NB * NN * NN;
    for (; i < tot; i += stride) {
        float v = S[i];
        S[i] = (v < thr) ? 0.f : v;
    }
}

// ---------------- support graph (fp32 + bf16 copies) ----------------
__global__ __launch_bounds__(256) void k_sup(const float* __restrict__ emb,
                                             float* __restrict__ sup,
                                             unsigned short* __restrict__ supB)
{
    int n = blockIdx.x, tid = threadIdx.x;
    __shared__ float en[16];
    if (tid < 16) en[tid] = emb[n * 16 + tid];
    __syncthreads();
    float v[4];
#pragma unroll
    for (int q = 0; q < 4; q++) {
        int m = q * 256 + tid;
        float d = 0.f;
#pragma unroll
        for (int dd = 0; dd < 16; dd++) d += en[dd] * emb[m * 16 + dd];
        v[q] = fmaxf(d, 0.f);
    }
    float mx = fmaxf(fmaxf(v[0], v[1]), fmaxf(v[2], v[3]));
    for (int o = 32; o > 0; o >>= 1) mx = fmaxf(mx, __shfl_xor(mx, o));
    __shared__ float red[4];
    if ((tid & 63) == 0) red[tid >> 6] = mx;
    __syncthreads();
    mx = fmaxf(fmaxf(red[0], red[1]), fmaxf(red[2], red[3]));
    float e[4];
    float s = 0.f;
#pragma unroll
    for (int q = 0; q < 4; q++) { e[q] = expf(v[q] - mx); s += e[q]; }
    for (int o = 32; o > 0; o >>= 1) s += __shfl_xor(s, o);
    __shared__ float red2[4];
    if ((tid & 63) == 0) red2[tid >> 6] = s;
    __syncthreads();
    s = red2[0] + red2[1] + red2[2] + red2[3];
    float inv = 1.f / s;
#pragma unroll
    for (int q = 0; q < 4; q++) {
        float val = e[q] * inv;
        sup[(size_t)n * NN + q * 256 + tid] = val;
        supB[(size_t)n * NN + q * 256 + tid] = cvt_bf(val);
    }
}

// A_t[b][m][n] = bf16(G[n][m] * spat[b][n][m])
__global__ __launch_bounds__(256) void k_prep(const float* __restrict__ G,
                                              const float* __restrict__ spat,
                                              unsigned short* __restrict__ At)
{
    __shared__ float tl[64][65];
    int b = blockIdx.z;
    int n0 = blockIdx.y * 64, m0 = blockIdx.x * 64;
    int tid = threadIdx.x;
    int c = tid & 63, r0 = tid >> 6;
    const float* sp = spat + (size_t)b * NN * NN;
    for (int i = 0; i < 16; i++) {
        int r = r0 + i * 4;
        tl[r][c] = G[(size_t)(n0 + r) * NN + m0 + c] * sp[(size_t)(n0 + r) * NN + m0 + c];
    }
    __syncthreads();
    int c2 = tid & 31, r4 = tid >> 5;
    unsigned short* ob = At + ((size_t)b * NN + m0) * NN + n0;
    for (int i = 0; i < 8; i++) {
        int rr = r4 + i * 8;
        unsigned int v0 = cvt_bf(tl[2 * c2][rr]);
        unsigned int v1 = cvt_bf(tl[2 * c2 + 1][rr]);
        *(unsigned int*)(ob + (size_t)rr * NN + 2 * c2) = v0 | (v1 << 16);
    }
}

// Xt[b][j][n] = bf16(x[b][n][j])
__global__ __launch_bounds__(256) void k_xt(const float* __restrict__ x,
                                            unsigned short* __restrict__ Xt)
{
    __shared__ float tl[64][65];
    int b = blockIdx.z;
    int n0 = blockIdx.y * 64, j0 = blockIdx.x * 64;
    int tid = threadIdx.x;
    int c = tid & 63, r0 = tid >> 6;
    for (int i = 0; i < 16; i++) {
        int r = r0 + i * 4;
        tl[r][c] = x[((size_t)b * NN + n0 + r) * 384 + j0 + c];
    }
    __syncthreads();
    int c2 = tid & 31, r4 = tid >> 5;
    unsigned short* ob = Xt + ((size_t)b * 384 + j0) * NN + n0;
    for (int i = 0; i < 8; i++) {
        int jj = r4 + i * 8;
        unsigned int v0 = cvt_bf(tl[2 * c2][jj]);
        unsigned int v1 = cvt_bf(tl[2 * c2 + 1][jj]);
        *(unsigned int*)(ob + (size_t)jj * NN + 2 * c2) = v0 | (v1 << 16);
    }
}

// ---------------- weight prep ----------------
// Wr[o][dt*64+c] = bf16( tcg[o]*tcv[o][c][dt]/||tcv[o]|| )
__global__ __launch_bounds__(192) void k_wnorm(const float* __restrict__ tcv,
                                               const float* __restrict__ tcg,
                                               unsigned short* __restrict__ Wr)
{
    int o = blockIdx.x, tid = threadIdx.x;
    float t = tcv[o * 192 + tid];
    float p = t * t;
    for (int off = 32; off > 0; off >>= 1) p += __shfl_xor(p, off);
    __shared__ float wsr[3];
    if ((tid & 63) == 0) wsr[tid >> 6] = p;
    __syncthreads();
    float sum = wsr[0] + wsr[1] + wsr[2];
    int c = tid / 3, dt = tid - c * 3;
    Wr[o * 192 + dt * 64 + c] = cvt_bf(t * (tcg[o] / sqrtf(sum)));
}

// Th[o][kind*32+f] = bf16(Theta[kind][f][o]);  Rc[o][f] = bf16(rcw[o][f])
__global__ __launch_bounds__(256) void k_prepw(const float* __restrict__ Theta,
                                               const float* __restrict__ rcw,
                                               unsigned short* __restrict__ Th,
                                               unsigned short* __restrict__ Rc)
{
    int tid = threadIdx.x;
    for (int i = tid; i < 6144; i += 256) {
        int o = i / 96, rem = i - o * 96;
        int kind = rem >> 5, f = rem & 31;
        Th[i] = cvt_bf(Theta[kind * 2048 + f * 64 + o]);
    }
    for (int i = tid; i < 2048; i += 256) Rc[i] = cvt_bf(rcw[i]);
}

// ---------------- MFMA fused tail ----------------
// Per block: 8 nodes x 12 t = 96 points, 64 channels. 4 waves (col split).
__global__ __launch_bounds__(256) void k_tail(const float* __restrict__ x,
                                              const unsigned short* __restrict__ h1,
                                              const unsigned short* __restrict__ h2,
                                              const float* __restrict__ spat,
                                              const unsigned short* __restrict__ Th,
                                              const unsigned short* __restrict__ Wr,
                                              const unsigned short* __restrict__ Rc,
                                              const float* __restrict__ tcb,
                                              const float* __restrict__ rcb,
                                              const float* __restrict__ lnw,
                                              const float* __restrict__ lnb,
                                              float* __restrict__ out)
{
    int b = blockIdx.y;
    int node0 = blockIdx.x * 8;
    int tid = threadIdx.x;
    int ln = tid & 63, wv = tid >> 6;
    int fr = ln & 15, fk = ln >> 4;

    // xt/h1t/h2t: [8 nodes][12 t][40 pad] bf16; gcn: [8][14][72] bf16; Y overlays: [96][65] f32
    __shared__ union {
        struct { unsigned short xt[3840], h1t[3840], h2t[3840], gcn[8064]; } a;
        float Y[96 * 65];
    } u;
    __shared__ float sdp[96];
    __shared__ float lnwS[64], lnbS[64], tbS[64];
    __shared__ float muS[96], rsS[96];

    size_t rowb = ((size_t)b * NN + node0) * 384;
    for (int i = tid; i < 3072; i += 256) {
        int node = i / 384, j = i - node * 384;
        int f = j / 12, t = j - f * 12;
        int la = node * 480 + t * 40 + f;
        u.a.xt[la]  = cvt_bf(x[rowb + i]);
        u.a.h1t[la] = h1[rowb + i];
        u.a.h2t[la] = h2[rowb + i];
    }
    for (int i = tid; i < 1152; i += 256) {      // zero conv-boundary rows 0 and 13
        int node = i / 144, r = i - node * 144;
        int rr = (r < 72) ? 0 : 13;
        u.a.gcn[node * 1008 + rr * 72 + (r % 72)] = 0;
    }
    if (tid < 96) {
        int node = tid / 12;
        sdp[tid] = spat[(size_t)b * NN * NN + (size_t)(node0 + node) * NN + node0 + node];
    }
    if (tid < 64) { lnwS[tid] = lnw[tid]; lnbS[tid] = lnb[tid]; tbS[tid] = tcb[tid] + rcb[tid]; }

    int ocol = wv * 16 + fr;
    bf16x8 bTh[3], bWr[6], bRc;
#pragma unroll
    for (int kb = 0; kb < 3; kb++)
        bTh[kb] = *(const bf16x8*)((const short*)Th + (size_t)ocol * 96 + kb * 32 + fk * 8);
#pragma unroll
    for (int kb = 0; kb < 6; kb++)
        bWr[kb] = *(const bf16x8*)((const short*)Wr + (size_t)ocol * 192 + kb * 32 + fk * 8);
    bRc = *(const bf16x8*)((const short*)Rc + (size_t)ocol * 32 + fk * 8);

    int na[6], ta[6];
#pragma unroll
    for (int rb = 0; rb < 6; rb++) {
        int p = rb * 16 + fr;
        na[rb] = p / 12; ta[rb] = p - na[rb] * 12;
    }
    __syncthreads();

    f32x4 acc[6];
    // GEMM1: gcn_pre = sd*(x@Th0) + h1@Th1 + h2@Th2
#pragma unroll
    for (int rb = 0; rb < 6; rb++) {
        int ax = na[rb] * 480 + ta[rb] * 40 + fk * 8;
        bf16x8 avx = *(const bf16x8*)(u.a.xt + ax);
        f32x4 z = (f32x4)(0.f);
        acc[rb] = __builtin_amdgcn_mfma_f32_16x16x32_bf16(avx, bTh[0], z, 0, 0, 0);
#pragma unroll
        for (int r = 0; r < 4; r++) acc[rb][r] *= sdp[rb * 16 + fk * 4 + r];
        bf16x8 av1 = *(const bf16x8*)(u.a.h1t + ax);
        acc[rb] = __builtin_amdgcn_mfma_f32_16x16x32_bf16(av1, bTh[1], acc[rb], 0, 0, 0);
        bf16x8 av2 = *(const bf16x8*)(u.a.h2t + ax);
        acc[rb] = __builtin_amdgcn_mfma_f32_16x16x32_bf16(av2, bTh[2], acc[rb], 0, 0, 0);
    }
    // relu -> gcn (row t+1; rows 0,13 stay zero)
#pragma unroll
    for (int rb = 0; rb < 6; rb++) {
#pragma unroll
        for (int r = 0; r < 4; r++) {
            int pc = rb * 16 + fk * 4 + r;
            int nc = pc / 12, tc2 = pc - nc * 12;
            u.a.gcn[nc * 1008 + (tc2 + 1) * 72 + wv * 16 + fr] = cvt_bf(fmaxf(acc[rb][r], 0.f));
        }
    }
    __syncthreads();
    // GEMM2 (time conv, K=192 over dt*64+c) + GEMM3 (residual, K=32)
#pragma unroll
    for (int rb = 0; rb < 6; rb++) {
        f32x4 a2 = (f32x4)(0.f);
#pragma unroll
        for (int kb = 0; kb < 6; kb++) {
            int dt = kb >> 1, c0 = (kb & 1) * 32;
            bf16x8 ag = *(const bf16x8*)(u.a.gcn + na[rb] * 1008 + (ta[rb] + dt) * 72 + c0 + fk * 8);
            a2 = __builtin_amdgcn_mfma_f32_16x16x32_bf16(ag, bWr[kb], a2, 0, 0, 0);
        }
        int ax = na[rb] * 480 + ta[rb] * 40 + fk * 8;
        bf16x8 avx = *(const bf16x8*)(u.a.xt + ax);
        acc[rb] = __builtin_amdgcn_mfma_f32_16x16x32_bf16(avx, bRc, a2, 0, 0, 0);
    }
    __syncthreads();   // all reads of union 'a' complete before Y overlays it
    float tb = tbS[ocol];
#pragma unroll
    for (int rb = 0; rb < 6; rb++)
#pragma unroll
        for (int r = 0; r < 4; r++)
            u.Y[(rb * 16 + fk * 4 + r) * 65 + ocol] = acc[rb][r] + tb;
    __syncthreads();
    if (tid < 96) {
        float s = 0.f, s2 = 0.f;
        for (int o = 0; o < 64; o++) {
            float v = u.Y[tid * 65 + o];
            s += v; s2 += v * v;
        }
        float mm = s * (1.f / 64.f);
        float var = s2 * (1.f / 64.f) - mm * mm;
        muS[tid] = mm; rsS[tid] = rsqrtf(var + 1e-5f);
    }
    __syncthreads();
    float* ob = out + rowb * 2;      // (b*NN+node0)*768
    for (int i = tid; i < 6144; i += 256) {
        int node = i / 768, rr = i - node * 768;
        int o = rr / 12, t = rr - o * 12;
        int p = node * 12 + t;
        ob[i] = (u.Y[p * 65 + o] - muS[p]) * rsS[p] * lnwS[o] + lnbS[o];
    }
}

extern "C" void kernel_launch(void* const* d_in, const int* in_sizes, int n_in,
                              void* d_out, int out_size, void* d_ws, size_t ws_size,
                              hipStream_t stream)
{
    const float* x    = (const float*)d_in[0];
    const float* emb  = (const float*)d_in[1];
    const float* W1   = (const float*)d_in[2];
    const float* W2   = (const float*)d_in[3];
    const float* W3   = (const float*)d_in[4];
    const float* bs   = (const float*)d_in[5];
    const float* Vs   = (const float*)d_in[6];
    const float* U1   = (const float*)d_in[7];
    const float* U2   = (const float*)d_in[8];
    const float* U3   = (const float*)d_in[9];
    const float* be   = (const float*)d_in[10];
    const float* Ve   = (const float*)d_in[11];
    const float* Theta= (const float*)d_in[12];
    const float* tcv  = (const float*)d_in[13];
    const float* tcg  = (const float*)d_in[14];
    const float* tcb  = (const float*)d_in[15];
    const float* rcw  = (const float*)d_in[16];
    const float* rcb  = (const float*)d_in[17];
    const float* lnw  = (const float*)d_in[18];
    const float* lnb  = (const float*)d_in[19];

    float* xres = (float*)d_out;                       // B*N*FT*T fp32
    float* spat = xres + (size_t)NB * NN * NFT * NT;   // B*N*N fp32

    char* base = (char*)d_ws;
    // [0,32MB): Pt (k_P_t -> mgemmS), then supB/supT (k_sup -> poly2), then At (k_prep -> mgemm h)
    unsigned short* Pt   = (unsigned short*)(base + 0);
    unsigned short* supB = (unsigned short*)(base + 0);
    unsigned short* supT = (unsigned short*)(base + 2097152);
    unsigned short* At   = (unsigned short*)(base + 0);
    // [32MB,...): xT fp32 -> reused as Xt bf16
    float*          xT  = (float*)(base + 33554432);
    unsigned short* Xt  = (unsigned short*)(base + 33554432);
    unsigned short* h1  = (unsigned short*)(base + 46137344);
    unsigned short* h2  = (unsigned short*)(base + 58720256);
    unsigned short* Vsb = (unsigned short*)(base + 71303168);
    float* bst     = (float*)(base + 73400320);
    float* sup     = (float*)(base + 77594624);
    float* poly2   = (float*)(base + 81788928);
    float* lhs_pre = (float*)(base + 85983232);
    float* lhs     = (float*)(base + 86007808);
    float* rhs     = (float*)(base + 86794240);
    float* prod    = (float*)(base + 87580672);
    float* E       = (float*)(base + 87589888);
    float* l2      = (float*)(base + 87599104);
    float* r2      = (float*)(base + 88385536);
    unsigned short* Wr = (unsigned short*)(base + 89171968);
    unsigned short* Th = (unsigned short*)(base + 89196544);
    unsigned short* Rc = (unsigned short*)(base + 89208832);
    float* gsum    = (float*)(base + 89221120);

    hipMemsetAsync(lhs_pre, 0, 6144 * sizeof(float), stream);
    hipMemsetAsync(gsum, 0, sizeof(float), stream);

    // temporal attention
    k_lhspre<<<dim3(16, 32), 384, 0, stream>>>(x, U1, lhs_pre);
    k_rhs<<<2048, 384, 0, stream>>>(x, U3, rhs);
    k_lhs<<<192, 256, 0, stream>>>(lhs_pre, U2, lhs);
    k_prod<<<2304, 64, 0, stream>>>(lhs, rhs, prod);
    k_E<<<16, 192, 0, stream>>>(prod, be, Ve, E);
    k_xTAt<<<dim3(128, 16), 384, 0, stream>>>(x, E, xT);
    // spatial attention
    k_l2r2<<<dim3(128, 16), 384, 0, stream>>>(xT, W1, W2, W3, l2, r2);
    k_tbs<<<dim3(16, 16), 256, 0, stream>>>(bs, bst);
    k_P_t<<<dim3(1024, 16), 256, 0, stream>>>(l2, r2, bst, Pt);
    k_cvt<<<1024, 256, 0, stream>>>(Vs, Vsb);
    mgemm<0><<<dim3(8, 8, 16), 256, 0, stream>>>((const short*)Vsb, (const short*)Pt,
        (void*)spat, NN, NN, NN, NN, 0L, (long)NN * NN, (long)NN * NN, 1.f, 0);
    k_softmax<<<dim3(16, 16), 256, 0, stream>>>(spat, gsum);
    k_thresh<<<2048, 256, 0, stream>>>(spat, gsum);
    // graph conv
    k_sup<<<1024, 256, 0, stream>>>(emb, sup, supB);
    k_tb16<<<dim3(16, 16), 256, 0, stream>>>(supB, supT);
    mgemm<0><<<dim3(8, 8, 1), 256, 0, stream>>>((const short*)supB, (const short*)supT,
        (void*)poly2, NN, NN, NN, NN, 0L, 0L, 0L, 2.f, 1);
    k_xt<<<dim3(6, 16, 16), 256, 0, stream>>>(x, Xt);
    k_prep<<<dim3(16, 16, 16), 256, 0, stream>>>(sup, spat, At);
    mgemm<1><<<dim3(3, 8, 16), 256, 0, stream>>>((const short*)At, (const short*)Xt,
        (void*)h1, NN, NN, NN, 384, (long)NN * NN, 384L * NN, (long)NN * 384, 1.f, 0);
    k_prep<<<dim3(16, 16, 16), 256, 0, stream>>>(poly2, spat, At);
    mgemm<1><<<dim3(3, 8, 16), 256, 0, stream>>>((const short*)At, (const short*)Xt,
        (void*)h2, NN, NN, NN, 384, (long)NN * NN, 384L * NN, (long)NN * 384, 1.f, 0);
    // tail
    k_wnorm<<<64, 192, 0, stream>>>(tcv, tcg, Wr);
    k_prepw<<<1, 256, 0, stream>>>(Theta, rcw, Th, Rc);
    k_tail<<<dim3(128, 16), 256, 0, stream>>>(x, h1, h2, spat, Th, Wr, Rc,
                                              tcb, rcb, lnw, lnb, xres);
}

// Round 4
// 380.507 us; speedup vs baseline: 5.1948x; 1.5954x over previous
//
#include <hip/hip_runtime.h>
#include <math.h>

#define NB 16      // B
#define NN 1024    // N
#define NF 32      // F
#define NT 12      // T
#define NFC 64
#define NFT 64

typedef __attribute__((ext_vector_type(8))) short bf16x8;
typedef __attribute__((ext_vector_type(4))) float f32x4;

__device__ inline unsigned short cvt_bf(float f) {
    unsigned int u = __float_as_uint(f);
    u += 0x7fff + ((u >> 16) & 1);
    return (unsigned short)(u >> 16);
}
__device__ inline float bf2f(unsigned short u) {
    return __uint_as_float(((unsigned int)u) << 16);
}
__device__ inline void gll16(const short* g, short* l) {
    __builtin_amdgcn_global_load_lds((const __attribute__((address_space(1))) void*)g,
                                     (__attribute__((address_space(3))) void*)l, 16, 0, 0);
}

// ---------------- temporal attention ----------------

__global__ __launch_bounds__(384) void k_lhspre(const float* __restrict__ x,
                                                const float* __restrict__ U1,
                                                float* __restrict__ lhs_pre)
{
    int b = blockIdx.x, ch = blockIdx.y, tid = threadIdx.x;
    int f = tid / 12, t = tid - f * 12;
    float acc = 0.f;
    int n0 = ch * 32;
    for (int n = n0; n < n0 + 32; n++)
        acc += x[((size_t)(b * NN + n)) * 384 + tid] * U1[n];
    atomicAdd(&lhs_pre[b * 384 + t * 32 + f], acc);
}

__global__ __launch_bounds__(384) void k_rhs(const float* __restrict__ x,
                                             const float* __restrict__ U3,
                                             float* __restrict__ rhs)
{
    __shared__ float sm[8 * 384];
    int tid = threadIdx.x;
    size_t r0 = (size_t)blockIdx.x * 8;
    for (int i = 0; i < 8; i++) sm[i * 384 + tid] = x[(r0 + i) * 384 + tid];
    __syncthreads();
    if (tid < 96) {
        int i = tid / 12, t = tid - i * 12;
        float s = 0.f;
        for (int f = 0; f < 32; f++) s += U3[f] * sm[i * 384 + f * 12 + t];
        rhs[(r0 + i) * 12 + t] = s;
    }
}

__global__ __launch_bounds__(256) void k_lhs(const float* __restrict__ lhs_pre,
                                             const float* __restrict__ U2,
                                             float* __restrict__ lhs)
{
    int bt = blockIdx.x;
    int tid = threadIdx.x;
    __shared__ float lp[32];
    if (tid < 32) lp[tid] = lhs_pre[bt * 32 + tid];
    __syncthreads();
    for (int q = 0; q < 4; q++) {
        int n = q * 256 + tid;
        float a = 0.f;
        for (int f = 0; f < 32; f++) a += lp[f] * U2[f * NN + n];
        lhs[(size_t)bt * NN + n] = a;
    }
}

__global__ __launch_bounds__(64) void k_prod(const float* __restrict__ lhs,
                                             const float* __restrict__ rhs,
                                             float* __restrict__ prod)
{
    int blk = blockIdx.x;
    int b = blk / 144, r = blk - b * 144;
    int s = r / 12, u = r - s * 12;
    int tid = threadIdx.x;
    float p = 0.f;
    for (int n = tid; n < NN; n += 64)
        p += lhs[((size_t)b * 12 + s) * NN + n] * rhs[((size_t)b * NN + n) * 12 + u];
    for (int o = 32; o > 0; o >>= 1) p += __shfl_xor(p, o);
    if (tid == 0) prod[blk] = p;
}

__global__ __launch_bounds__(192) void k_E(const float* __restrict__ prod,
                                           const float* __restrict__ be,
                                           const float* __restrict__ Ve,
                                           float* __restrict__ E)
{
    int b = blockIdx.x, tid = threadIdx.x;
    __shared__ float ssig[144], sE[144], mx[12], sm[12];
    if (tid < 144) ssig[tid] = 1.f / (1.f + expf(-(prod[b * 144 + tid] + be[tid])));
    __syncthreads();
    if (tid < 144) {
        int t = tid / 12, u = tid - t * 12;
        float a = 0.f;
        for (int s2 = 0; s2 < 12; s2++) a += Ve[t * 12 + s2] * ssig[s2 * 12 + u];
        sE[tid] = a;
    }
    __syncthreads();
    if (tid < 12) {
        float m = -1e30f;
        for (int t = 0; t < 12; t++) m = fmaxf(m, sE[t * 12 + tid]);
        float s = 0.f;
        for (int t = 0; t < 12; t++) s += expf(sE[t * 12 + tid] - m);
        mx[tid] = m; sm[tid] = s;
    }
    __syncthreads();
    if (tid < 144) {
        int u = tid % 12;
        E[b * 144 + tid] = expf(sE[tid] - mx[u]) / sm[u];
    }
}

__global__ __launch_bounds__(384) void k_xTAt(const float* __restrict__ x,
                                              const float* __restrict__ E,
                                              float* __restrict__ xT)
{
    __shared__ float xs[8 * 384], Es[144];
    int b = blockIdx.y, tid = threadIdx.x;
    size_t r0 = (size_t)b * NN + (size_t)blockIdx.x * 8;
    if (tid < 144) Es[tid] = E[b * 144 + tid];
    for (int i = 0; i < 8; i++) xs[i * 384 + tid] = x[(r0 + i) * 384 + tid];
    __syncthreads();
    int f = tid / 12, u = tid - f * 12;
    for (int i = 0; i < 8; i++) {
        float a = 0.f;
#pragma unroll
        for (int t = 0; t < 12; t++) a += xs[i * 384 + f * 12 + t] * Es[t * 12 + u];
        xT[(r0 + i) * 384 + f * 12 + u] = a;
    }
}

// ---------------- spatial attention ----------------

__global__ __launch_bounds__(384) void k_l2r2(const float* __restrict__ xT,
                                              const float* __restrict__ W1,
                                              const float* __restrict__ W2,
                                              const float* __restrict__ W3,
                                              float* __restrict__ l2,
                                              float* __restrict__ r2)
{
    __shared__ float xs[8 * 384];
    __shared__ float lp[8][32];
    int b = blockIdx.y, tid = threadIdx.x;
    int n0 = blockIdx.x * 8;
    size_t r0 = (size_t)b * NN + n0;
    for (int i = 0; i < 8; i++) xs[i * 384 + tid] = xT[(r0 + i) * 384 + tid];
    __syncthreads();
    if (tid < 256) {
        int i = tid >> 5, f = tid & 31;
        float a = 0.f;
#pragma unroll
        for (int t = 0; t < 12; t++) a += xs[i * 384 + f * 12 + t] * W1[t];
        lp[i][f] = a;
    }
    __syncthreads();
    if (tid < 96) {
        int i = tid / 12, t = tid - i * 12;
        float a = 0.f, rr = 0.f;
        for (int f = 0; f < 32; f++) {
            a += lp[i][f] * W2[f * 12 + t];
            rr += W3[f] * xs[i * 384 + f * 12 + t];
        }
        l2[(r0 + i) * 12 + t] = a;
        r2[((size_t)b * 12 + t) * NN + n0 + i] = rr;
    }
}

// bs_t[k][m] = bs[m][k]
__global__ __launch_bounds__(256) void k_tbs(const float* __restrict__ bsin,
                                             float* __restrict__ bst)
{
    __shared__ float tl[64][65];
    int m0 = blockIdx.y * 64, k0 = blockIdx.x * 64;
    int tid = threadIdx.x;
    int c = tid & 63, r0 = tid >> 6;
    for (int i = 0; i < 16; i++) {
        int r = r0 + i * 4;
        tl[r][c] = bsin[(size_t)(m0 + r) * NN + k0 + c];
    }
    __syncthreads();
    for (int i = 0; i < 16; i++) {
        int r = r0 + i * 4;
        bst[(size_t)(k0 + r) * NN + m0 + c] = tl[c][r];
    }
}

// P_t[b][k][m] = bf16(sigmoid(sum_t l2[b,m,t]*r2[b,t,k] + bs[m,k]))
__global__ __launch_bounds__(256) void k_P_t(const float* __restrict__ l2,
                                             const float* __restrict__ r2,
                                             const float* __restrict__ bst,
                                             unsigned short* __restrict__ Pt)
{
    int b = blockIdx.y, k = blockIdx.x;
    int tid = threadIdx.x;
    float rv[12];
#pragma unroll
    for (int t = 0; t < 12; t++) rv[t] = r2[((size_t)b * 12 + t) * NN + k];
    for (int q = 0; q < 4; q++) {
        int m = q * 256 + tid;
        const float* lp = &l2[((size_t)b * NN + m) * 12];
        float p = 0.f;
#pragma unroll
        for (int t = 0; t < 12; t++) p += lp[t] * rv[t];
        p += bst[(size_t)k * NN + m];
        float sg = 1.f / (1.f + expf(-p));
        Pt[((size_t)b * NN + k) * NN + m] = cvt_bf(sg);
    }
}

// Vs fp32 -> bf16
__global__ __launch_bounds__(256) void k_cvt(const float* __restrict__ s,
                                             unsigned short* __restrict__ d)
{
    size_t i = ((size_t)blockIdx.x * 256 + threadIdx.x) * 4;
    float4 v = *(const float4*)(s + i);
    unsigned int p0 = (unsigned int)cvt_bf(v.x) | ((unsigned int)cvt_bf(v.y) << 16);
    unsigned int p1 = (unsigned int)cvt_bf(v.z) | ((unsigned int)cvt_bf(v.w) << 16);
    *(unsigned int*)(d + i) = p0;
    *(unsigned int*)(d + i + 2) = p1;
}

// bf16 transpose 1024x1024
__global__ __launch_bounds__(256) void k_tb16(const unsigned short* __restrict__ s,
                                              unsigned short* __restrict__ d)
{
    __shared__ unsigned short tl[64][65];
    int r0 = blockIdx.y * 64, c0 = blockIdx.x * 64;
    int tid = threadIdx.x;
    int c = tid & 63, rr = tid >> 6;
    for (int i = 0; i < 16; i++)
        tl[rr + i * 4][c] = s[(size_t)(r0 + rr + i * 4) * NN + c0 + c];
    __syncthreads();
    for (int i = 0; i < 16; i++)
        d[(size_t)(c0 + rr + i * 4) * NN + r0 + c] = tl[c][rr + i * 4];
}

// ---------------- MFMA bf16 NT GEMM ----------------
// MODE 0: fp32 out (alpha, subI). MODE 1: bf16 out. MODE 2: fp32 exp(out) + colsum atomics.
template<int MODE>
__global__ __launch_bounds__(256) void mgemm(const short* __restrict__ A,
                                             const short* __restrict__ B,
                                             void* __restrict__ Cv,
                                             int Kd, int ldA, int ldB, int ldC,
                                             long sA, long sB, long sC,
                                             float alpha, int subI,
                                             float* __restrict__ colsum)
{
    int bz = blockIdx.z;
    const short* Ab = A + (size_t)bz * sA;
    const short* Bb = B + (size_t)bz * sB;
    int i0 = blockIdx.y * 128, j0 = blockIdx.x * 128;
    __shared__ short sm[16384];            // As [128][64] @0, Bs [128][64] @8192
    int tid = threadIdx.x;
    int ln = tid & 63, wv = tid >> 6;
    int wm = (wv >> 1) * 64, wn = (wv & 1) * 64;
    int fr = ln & 15, fk = ln >> 4;
    f32x4 acc[4][4];
#pragma unroll
    for (int a = 0; a < 4; a++)
#pragma unroll
        for (int b2 = 0; b2 < 4; b2++) acc[a][b2] = (f32x4)(0.f);

    for (int k0 = 0; k0 < Kd; k0 += 64) {
#pragma unroll
        for (int q = 0; q < 4; q++) {
            int e = q * 2048 + tid * 8;
            const short* src = Ab + (size_t)(i0 + (e >> 6)) * ldA + k0 + (e & 63);
            gll16(src, sm + e);
        }
#pragma unroll
        for (int q = 0; q < 4; q++) {
            int e = q * 2048 + tid * 8;
            const short* src = Bb + (size_t)(j0 + (e >> 6)) * ldB + k0 + (e & 63);
            gll16(src, sm + 8192 + e);
        }
        __syncthreads();
#pragma unroll
        for (int ks = 0; ks < 2; ks++) {
            bf16x8 av[4], bv[4];
#pragma unroll
            for (int mi = 0; mi < 4; mi++)
                av[mi] = *(const bf16x8*)(sm + (wm + mi * 16 + fr) * 64 + ks * 32 + fk * 8);
#pragma unroll
            for (int nj = 0; nj < 4; nj++)
                bv[nj] = *(const bf16x8*)(sm + 8192 + (wn + nj * 16 + fr) * 64 + ks * 32 + fk * 8);
#pragma unroll
            for (int mi = 0; mi < 4; mi++)
#pragma unroll
                for (int nj = 0; nj < 4; nj++)
                    acc[mi][nj] = __builtin_amdgcn_mfma_f32_16x16x32_bf16(av[mi], bv[nj], acc[mi][nj], 0, 0, 0);
        }
        __syncthreads();
    }
    if constexpr (MODE == 2) {
        float* Cb = (float*)Cv + (size_t)bz * sC;
#pragma unroll
        for (int nj = 0; nj < 4; nj++) {
            float cs = 0.f;
            int col = j0 + wn + nj * 16 + fr;
#pragma unroll
            for (int mi = 0; mi < 4; mi++) {
                int row = i0 + wm + mi * 16 + fk * 4;
#pragma unroll
                for (int r = 0; r < 4; r++) {
                    float e = expf(acc[mi][nj][r]);
                    Cb[(size_t)(row + r) * ldC + col] = e;
                    cs += e;
                }
            }
            cs += __shfl_xor(cs, 16);
            cs += __shfl_xor(cs, 32);
            if (ln < 16) atomicAdd(&colsum[(size_t)bz * NN + col], cs);
        }
    } else {
#pragma unroll
        for (int mi = 0; mi < 4; mi++)
#pragma unroll
            for (int nj = 0; nj < 4; nj++) {
                int row = i0 + wm + mi * 16 + fk * 4;
                int col = j0 + wn + nj * 16 + fr;
                if constexpr (MODE == 1) {
                    unsigned short* Cb = (unsigned short*)Cv + (size_t)bz * sC;
#pragma unroll
                    for (int r = 0; r < 4; r++)
                        Cb[(size_t)(row + r) * ldC + col] = cvt_bf(alpha * acc[mi][nj][r]);
                } else {
                    float* Cb = (float*)Cv + (size_t)bz * sC;
#pragma unroll
                    for (int r = 0; r < 4; r++) {
                        float v = alpha * acc[mi][nj][r];
                        if (subI && (row + r) == col) v -= 1.f;
                        Cb[(size_t)(row + r) * ldC + col] = v;
                    }
                }
            }
    }
}

// ---------------- normalize + threshold + At1 prep (fused) ----------------
// spat holds exp(S); out: spat = thresholded Sn; At1[b][m][n] = bf16(sup[n][m]*Sn)
__global__ __launch_bounds__(256) void k_normprep(float* __restrict__ spat,
                                                  const float* __restrict__ colsum,
                                                  const float* __restrict__ sup,
                                                  unsigned short* __restrict__ At1)
{
    __shared__ unsigned short t1[64][66];
    int b = blockIdx.z;
    int n0 = blockIdx.y * 64, m0 = blockIdx.x * 64;
    int tid = threadIdx.x;
    int c = tid & 63, r0 = tid >> 6;
    const float thr = (1.0f / 1024.0f) / 0.6f;
    float inv = 1.f / colsum[(size_t)b * NN + m0 + c];
    float* sp = spat + (size_t)b * NN * NN;
    for (int i = 0; i < 16; i++) {
        int r = r0 + i * 4;
        size_t idx = (size_t)(n0 + r) * NN + m0 + c;
        float v = sp[idx] * inv;
        v = (v < thr) ? 0.f : v;
        sp[idx] = v;
        t1[r][c] = cvt_bf(sup[(size_t)(n0 + r) * NN + m0 + c] * v);
    }
    __syncthreads();
    int c2 = tid & 31, r4 = tid >> 5;
    unsigned short* ob = At1 + ((size_t)b * NN + m0) * NN + n0;
    for (int i = 0; i < 8; i++) {
        int rr = r4 + i * 8;
        unsigned int v0 = (unsigned int)t1[2 * c2][rr] | ((unsigned int)t1[2 * c2 + 1][rr] << 16);
        *(unsigned int*)(ob + (size_t)rr * NN + 2 * c2) = v0;
    }
}

// ---------------- support graph (fp32 + bf16 copies) ----------------
__global__ __launch_bounds__(256) void k_sup(const float* __restrict__ emb,
                                             float* __restrict__ sup,
                                             unsigned short* __restrict__ supB)
{
    int n = blockIdx.x, tid = threadIdx.x;
    __shared__ float en[16];
    if (tid < 16) en[tid] = emb[n * 16 + tid];
    __syncthreads();
    float v[4];
#pragma unroll
    for (int q = 0; q < 4; q++) {
        int m = q * 256 + tid;
        float d = 0.f;
#pragma unroll
        for (int dd = 0; dd < 16; dd++) d += en[dd] * emb[m * 16 + dd];
        v[q] = fmaxf(d, 0.f);
    }
    float mx = fmaxf(fmaxf(v[0], v[1]), fmaxf(v[2], v[3]));
    for (int o = 32; o > 0; o >>= 1) mx = fmaxf(mx, __shfl_xor(mx, o));
    __shared__ float red[4];
    if ((tid & 63) == 0) red[tid >> 6] = mx;
    __syncthreads();
    mx = fmaxf(fmaxf(red[0], red[1]), fmaxf(red[2], red[3]));
    float e[4];
    float s = 0.f;
#pragma unroll
    for (int q = 0; q < 4; q++) { e[q] = expf(v[q] - mx); s += e[q]; }
    for (int o = 32; o > 0; o >>= 1) s += __shfl_xor(s, o);
    __shared__ float red2[4];
    if ((tid & 63) == 0) red2[tid >> 6] = s;
    __syncthreads();
    s = red2[0] + red2[1] + red2[2] + red2[3];
    float inv = 1.f / s;
#pragma unroll
    for (int q = 0; q < 4; q++) {
        float val = e[q] * inv;
        sup[(size_t)n * NN + q * 256 + tid] = val;
        supB[(size_t)n * NN + q * 256 + tid] = cvt_bf(val);
    }
}

// A_t[b][m][n] = bf16(G[n][m] * spat[b][n][m])
__global__ __launch_bounds__(256) void k_prep(const float* __restrict__ G,
                                              const float* __restrict__ spat,
                                              unsigned short* __restrict__ At)
{
    __shared__ float tl[64][65];
    int b = blockIdx.z;
    int n0 = blockIdx.y * 64, m0 = blockIdx.x * 64;
    int tid = threadIdx.x;
    int c = tid & 63, r0 = tid >> 6;
    const float* sp = spat + (size_t)b * NN * NN;
    for (int i = 0; i < 16; i++) {
        int r = r0 + i * 4;
        tl[r][c] = G[(size_t)(n0 + r) * NN + m0 + c] * sp[(size_t)(n0 + r) * NN + m0 + c];
    }
    __syncthreads();
    int c2 = tid & 31, r4 = tid >> 5;
    unsigned short* ob = At + ((size_t)b * NN + m0) * NN + n0;
    for (int i = 0; i < 8; i++) {
        int rr = r4 + i * 8;
        unsigned int v0 = cvt_bf(tl[2 * c2][rr]);
        unsigned int v1 = cvt_bf(tl[2 * c2 + 1][rr]);
        *(unsigned int*)(ob + (size_t)rr * NN + 2 * c2) = v0 | (v1 << 16);
    }
}

// Xt[b][j][n] = bf16(x[b][n][j])
__global__ __launch_bounds__(256) void k_xt(const float* __restrict__ x,
                                            unsigned short* __restrict__ Xt)
{
    __shared__ float tl[64][65];
    int b = blockIdx.z;
    int n0 = blockIdx.y * 64, j0 = blockIdx.x * 64;
    int tid = threadIdx.x;
    int c = tid & 63, r0 = tid >> 6;
    for (int i = 0; i < 16; i++) {
        int r = r0 + i * 4;
        tl[r][c] = x[((size_t)b * NN + n0 + r) * 384 + j0 + c];
    }
    __syncthreads();
    int c2 = tid & 31, r4 = tid >> 5;
    unsigned short* ob = Xt + ((size_t)b * 384 + j0) * NN + n0;
    for (int i = 0; i < 8; i++) {
        int jj = r4 + i * 8;
        unsigned int v0 = cvt_bf(tl[2 * c2][jj]);
        unsigned int v1 = cvt_bf(tl[2 * c2 + 1][jj]);
        *(unsigned int*)(ob + (size_t)jj * NN + 2 * c2) = v0 | (v1 << 16);
    }
}

// ---------------- weight prep ----------------
__global__ __launch_bounds__(192) void k_wnorm(const float* __restrict__ tcv,
                                               const float* __restrict__ tcg,
                                               unsigned short* __restrict__ Wr)
{
    int o = blockIdx.x, tid = threadIdx.x;
    float t = tcv[o * 192 + tid];
    float p = t * t;
    for (int off = 32; off > 0; off >>= 1) p += __shfl_xor(p, off);
    __shared__ float wsr[3];
    if ((tid & 63) == 0) wsr[tid >> 6] = p;
    __syncthreads();
    float sum = wsr[0] + wsr[1] + wsr[2];
    int c = tid / 3, dt = tid - c * 3;
    Wr[o * 192 + dt * 64 + c] = cvt_bf(t * (tcg[o] / sqrtf(sum)));
}

__global__ __launch_bounds__(256) void k_prepw(const float* __restrict__ Theta,
                                               const float* __restrict__ rcw,
                                               unsigned short* __restrict__ Th,
                                               unsigned short* __restrict__ Rc)
{
    int tid = threadIdx.x;
    for (int i = tid; i < 6144; i += 256) {
        int o = i / 96, rem = i - o * 96;
        int kind = rem >> 5, f = rem & 31;
        Th[i] = cvt_bf(Theta[kind * 2048 + f * 64 + o]);
    }
    for (int i = tid; i < 2048; i += 256) Rc[i] = cvt_bf(rcw[i]);
}

// ---------------- MFMA fused tail ----------------
__global__ __launch_bounds__(256) void k_tail(const float* __restrict__ x,
                                              const unsigned short* __restrict__ h1,
                                              const unsigned short* __restrict__ h2,
                                              const float* __restrict__ spat,
                                              const unsigned short* __restrict__ Th,
                                              const unsigned short* __restrict__ Wr,
                                              const unsigned short* __restrict__ Rc,
                                              const float* __restrict__ tcb,
                                              const float* __restrict__ rcb,
                                              const float* __restrict__ lnw,
                                              const float* __restrict__ lnb,
                                              float* __restrict__ out)
{
    int b = blockIdx.y;
    int node0 = blockIdx.x * 8;
    int tid = threadIdx.x;
    int ln = tid & 63, wv = tid >> 6;
    int fr = ln & 15, fk = ln >> 4;

    __shared__ union {
        struct { unsigned short xt[3840], h1t[3840], h2t[3840], gcn[8064]; } a;
        float Y[96 * 65];
    } u;
    __shared__ float sdp[96];
    __shared__ float lnwS[64], lnbS[64], tbS[64];
    __shared__ float muS[96], rsS[96];

    size_t rowb = ((size_t)b * NN + node0) * 384;
    for (int i = tid; i < 3072; i += 256) {
        int node = i / 384, j = i - node * 384;
        int f = j / 12, t = j - f * 12;
        int la = node * 480 + t * 40 + f;
        u.a.xt[la]  = cvt_bf(x[rowb + i]);
        u.a.h1t[la] = h1[rowb + i];
        u.a.h2t[la] = h2[rowb + i];
    }
    for (int i = tid; i < 1152; i += 256) {
        int node = i / 144, r = i - node * 144;
        int rr = (r < 72) ? 0 : 13;
        u.a.gcn[node * 1008 + rr * 72 + (r % 72)] = 0;
    }
    if (tid < 96) {
        int node = tid / 12;
        sdp[tid] = spat[(size_t)b * NN * NN + (size_t)(node0 + node) * NN + node0 + node];
    }
    if (tid < 64) { lnwS[tid] = lnw[tid]; lnbS[tid] = lnb[tid]; tbS[tid] = tcb[tid] + rcb[tid]; }

    int ocol = wv * 16 + fr;
    bf16x8 bTh[3], bWr[6], bRc;
#pragma unroll
    for (int kb = 0; kb < 3; kb++)
        bTh[kb] = *(const bf16x8*)((const short*)Th + (size_t)ocol * 96 + kb * 32 + fk * 8);
#pragma unroll
    for (int kb = 0; kb < 6; kb++)
        bWr[kb] = *(const bf16x8*)((const short*)Wr + (size_t)ocol * 192 + kb * 32 + fk * 8);
    bRc = *(const bf16x8*)((const short*)Rc + (size_t)ocol * 32 + fk * 8);

    int na[6], ta[6];
#pragma unroll
    for (int rb = 0; rb < 6; rb++) {
        int p = rb * 16 + fr;
        na[rb] = p / 12; ta[rb] = p - na[rb] * 12;
    }
    __syncthreads();

    f32x4 acc[6];
#pragma unroll
    for (int rb = 0; rb < 6; rb++) {
        int ax = na[rb] * 480 + ta[rb] * 40 + fk * 8;
        bf16x8 avx = *(const bf16x8*)(u.a.xt + ax);
        f32x4 z = (f32x4)(0.f);
        acc[rb] = __builtin_amdgcn_mfma_f32_16x16x32_bf16(avx, bTh[0], z, 0, 0, 0);
#pragma unroll
        for (int r = 0; r < 4; r++) acc[rb][r] *= sdp[rb * 16 + fk * 4 + r];
        bf16x8 av1 = *(const bf16x8*)(u.a.h1t + ax);
        acc[rb] = __builtin_amdgcn_mfma_f32_16x16x32_bf16(av1, bTh[1], acc[rb], 0, 0, 0);
        bf16x8 av2 = *(const bf16x8*)(u.a.h2t + ax);
        acc[rb] = __builtin_amdgcn_mfma_f32_16x16x32_bf16(av2, bTh[2], acc[rb], 0, 0, 0);
    }
#pragma unroll
    for (int rb = 0; rb < 6; rb++) {
#pragma unroll
        for (int r = 0; r < 4; r++) {
            int pc = rb * 16 + fk * 4 + r;
            int nc = pc / 12, tc2 = pc - nc * 12;
            u.a.gcn[nc * 1008 + (tc2 + 1) * 72 + wv * 16 + fr] = cvt_bf(fmaxf(acc[rb][r], 0.f));
        }
    }
    __syncthreads();
#pragma unroll
    for (int rb = 0; rb < 6; rb++) {
        f32x4 a2 = (f32x4)(0.f);
#pragma unroll
        for (int kb = 0; kb < 6; kb++) {
            int dt = kb >> 1, c0 = (kb & 1) * 32;
            bf16x8 ag = *(const bf16x8*)(u.a.gcn + na[rb] * 1008 + (ta[rb] + dt) * 72 + c0 + fk * 8);
            a2 = __builtin_amdgcn_mfma_f32_16x16x32_bf16(ag, bWr[kb], a2, 0, 0, 0);
        }
        int ax = na[rb] * 480 + ta[rb] * 40 + fk * 8;
        bf16x8 avx = *(const bf16x8*)(u.a.xt + ax);
        acc[rb] = __builtin_amdgcn_mfma_f32_16x16x32_bf16(avx, bRc, a2, 0, 0, 0);
    }
    __syncthreads();
    float tb = tbS[ocol];
#pragma unroll
    for (int rb = 0; rb < 6; rb++)
#pragma unroll
        for (int r = 0; r < 4; r++)
            u.Y[(rb * 16 + fk * 4 + r) * 65 + ocol] = acc[rb][r] + tb;
    __syncthreads();
    if (tid < 96) {
        float s = 0.f, s2 = 0.f;
        for (int o = 0; o < 64; o++) {
            float v = u.Y[tid * 65 + o];
            s += v; s2 += v * v;
        }
        float mm = s * (1.f / 64.f);
        float var = s2 * (1.f / 64.f) - mm * mm;
        muS[tid] = mm; rsS[tid] = rsqrtf(var + 1e-5f);
    }
    __syncthreads();
    float* ob = out + rowb * 2;
    for (int i = tid; i < 6144; i += 256) {
        int node = i / 768, rr = i - node * 768;
        int o = rr / 12, t = rr - o * 12;
        int p = node * 12 + t;
        ob[i] = (u.Y[p * 65 + o] - muS[p]) * rsS[p] * lnwS[o] + lnbS[o];
    }
}

extern "C" void kernel_launch(void* const* d_in, const int* in_sizes, int n_in,
                              void* d_out, int out_size, void* d_ws, size_t ws_size,
                              hipStream_t stream)
{
    const float* x    = (const float*)d_in[0];
    const float* emb  = (const float*)d_in[1];
    const float* W1   = (const float*)d_in[2];
    const float* W2   = (const float*)d_in[3];
    const float* W3   = (const float*)d_in[4];
    const float* bs   = (const float*)d_in[5];
    const float* Vs   = (const float*)d_in[6];
    const float* U1   = (const float*)d_in[7];
    const float* U2   = (const float*)d_in[8];
    const float* U3   = (const float*)d_in[9];
    const float* be   = (const float*)d_in[10];
    const float* Ve   = (const float*)d_in[11];
    const float* Theta= (const float*)d_in[12];
    const float* tcv  = (const float*)d_in[13];
    const float* tcg  = (const float*)d_in[14];
    const float* tcb  = (const float*)d_in[15];
    const float* rcw  = (const float*)d_in[16];
    const float* rcb  = (const float*)d_in[17];
    const float* lnw  = (const float*)d_in[18];
    const float* lnb  = (const float*)d_in[19];

    float* xres = (float*)d_out;                       // B*N*FT*T fp32
    float* spat = xres + (size_t)NB * NN * NFT * NT;   // B*N*N fp32

    char* base = (char*)d_ws;
    unsigned short* Pt   = (unsigned short*)(base + 0);
    unsigned short* supB = (unsigned short*)(base + 0);
    unsigned short* supT = (unsigned short*)(base + 2097152);
    unsigned short* At   = (unsigned short*)(base + 0);   // At1 (normprep), then At2 (k_prep)
    float*          xT  = (float*)(base + 33554432);
    unsigned short* Xt  = (unsigned short*)(base + 33554432);
    unsigned short* h1  = (unsigned short*)(base + 46137344);
    unsigned short* h2  = (unsigned short*)(base + 58720256);
    unsigned short* Vsb = (unsigned short*)(base + 71303168);
    float* bst     = (float*)(base + 73400320);           // dead after k_P_t
    float* colsum  = (float*)(base + 73400320);           // reuses bst region (64 KB)
    float* sup     = (float*)(base + 77594624);
    float* poly2   = (float*)(base + 81788928);
    float* lhs_pre = (float*)(base + 85983232);
    float* lhs     = (float*)(base + 86007808);
    float* rhs     = (float*)(base + 86794240);
    float* prod    = (float*)(base + 87580672);
    float* E       = (float*)(base + 87589888);
    float* l2      = (float*)(base + 87599104);
    float* r2      = (float*)(base + 88385536);
    unsigned short* Wr = (unsigned short*)(base + 89171968);
    unsigned short* Th = (unsigned short*)(base + 89196544);
    unsigned short* Rc = (unsigned short*)(base + 89208832);

    hipMemsetAsync(lhs_pre, 0, 6144 * sizeof(float), stream);

    // temporal attention
    k_lhspre<<<dim3(16, 32), 384, 0, stream>>>(x, U1, lhs_pre);
    k_rhs<<<2048, 384, 0, stream>>>(x, U3, rhs);
    k_lhs<<<192, 256, 0, stream>>>(lhs_pre, U2, lhs);
    k_prod<<<2304, 64, 0, stream>>>(lhs, rhs, prod);
    k_E<<<16, 192, 0, stream>>>(prod, be, Ve, E);
    k_xTAt<<<dim3(128, 16), 384, 0, stream>>>(x, E, xT);
    // spatial attention
    k_l2r2<<<dim3(128, 16), 384, 0, stream>>>(xT, W1, W2, W3, l2, r2);
    k_tbs<<<dim3(16, 16), 256, 0, stream>>>(bs, bst);
    k_P_t<<<dim3(1024, 16), 256, 0, stream>>>(l2, r2, bst, Pt);
    k_cvt<<<1024, 256, 0, stream>>>(Vs, Vsb);
    hipMemsetAsync(colsum, 0, (size_t)NB * NN * sizeof(float), stream);  // bst dead now
    mgemm<2><<<dim3(8, 8, 16), 256, 0, stream>>>((const short*)Vsb, (const short*)Pt,
        (void*)spat, NN, NN, NN, NN, 0L, (long)NN * NN, (long)NN * NN, 1.f, 0, colsum);
    // graph conv
    k_sup<<<1024, 256, 0, stream>>>(emb, sup, supB);
    k_tb16<<<dim3(16, 16), 256, 0, stream>>>(supB, supT);
    mgemm<0><<<dim3(8, 8, 1), 256, 0, stream>>>((const short*)supB, (const short*)supT,
        (void*)poly2, NN, NN, NN, NN, 0L, 0L, 0L, 2.f, 1, nullptr);
    // normalize + threshold + At1 (sup-masked), all fused
    k_normprep<<<dim3(16, 16, 16), 256, 0, stream>>>(spat, colsum, sup, At);
    k_xt<<<dim3(6, 16, 16), 256, 0, stream>>>(x, Xt);
    mgemm<1><<<dim3(3, 8, 16), 256, 0, stream>>>((const short*)At, (const short*)Xt,
        (void*)h1, NN, NN, NN, 384, (long)NN * NN, 384L * NN, (long)NN * 384, 1.f, 0, nullptr);
    k_prep<<<dim3(16, 16, 16), 256, 0, stream>>>(poly2, spat, At);
    mgemm<1><<<dim3(3, 8, 16), 256, 0, stream>>>((const short*)At, (const short*)Xt,
        (void*)h2, NN, NN, NN, 384, (long)NN * NN, 384L * NN, (long)NN * 384, 1.f, 0, nullptr);
    // tail
    k_wnorm<<<64, 192, 0, stream>>>(tcv, tcg, Wr);
    k_prepw<<<1, 256, 0, stream>>>(Theta, rcw, Th, Rc);
    k_tail<<<dim3(128, 16), 256, 0, stream>>>(x, h1, h2, spat, Th, Wr, Rc,
                                              tcb, rcb, lnw, lnb, xres);
}

// Round 5
// 367.412 us; speedup vs baseline: 5.3799x; 1.0356x over previous
//
#include <hip/hip_runtime.h>
#include <math.h>

#define NB 16      // B
#define NN 1024    // N
#define NF 32      // F
#define NT 12      // T
#define NFC 64
#define NFT 64

typedef __attribute__((ext_vector_type(8))) short bf16x8;
typedef __attribute__((ext_vector_type(4))) float f32x4;

__device__ inline unsigned short cvt_bf(float f) {
    unsigned int u = __float_as_uint(f);
    u += 0x7fff + ((u >> 16) & 1);
    return (unsigned short)(u >> 16);
}
__device__ inline void gll16(const short* g, short* l) {
    __builtin_amdgcn_global_load_lds((const __attribute__((address_space(1))) void*)g,
                                     (__attribute__((address_space(3))) void*)l, 16, 0, 0);
}

// ---------------- fused pre-pass: lhs_pre (U1), rhs (U3), rr3 (W3) ----------------
// grid (16 b, 16 ch) x 384
__global__ __launch_bounds__(384) void k_pre(const float* __restrict__ x,
                                             const float* __restrict__ U1,
                                             const float* __restrict__ U3,
                                             const float* __restrict__ W3,
                                             float* __restrict__ lhs_pre,
                                             float* __restrict__ rhs,
                                             float* __restrict__ rr3)
{
    __shared__ float xs[8 * 384];
    int b = blockIdx.x, ch = blockIdx.y, tid = threadIdx.x;
    float acc = 0.f;
    for (int c8 = 0; c8 < 8; c8++) {
        int n0 = ch * 64 + c8 * 8;
        size_t r0 = (size_t)b * NN + n0;
        __syncthreads();
        for (int i = 0; i < 8; i++) xs[i * 384 + tid] = x[(r0 + i) * 384 + tid];
        __syncthreads();
        for (int i = 0; i < 8; i++) acc += xs[i * 384 + tid] * U1[n0 + i];
        if (tid < 192) {
            int half = tid / 96;
            int r = tid - half * 96;
            int i = r / 12, t = r - i * 12;
            const float* wv = half ? W3 : U3;
            float s = 0.f;
            for (int f = 0; f < 32; f++) s += wv[f] * xs[i * 384 + f * 12 + t];
            float* outp = half ? rr3 : rhs;
            outp[(r0 + i) * 12 + t] = s;
        }
    }
    int f = tid / 12, t = tid - f * 12;
    atomicAdd(&lhs_pre[b * 384 + t * 32 + f], acc);
}

__global__ __launch_bounds__(256) void k_lhs(const float* __restrict__ lhs_pre,
                                             const float* __restrict__ U2,
                                             float* __restrict__ lhs)
{
    int bt = blockIdx.x;
    int tid = threadIdx.x;
    __shared__ float lp[32];
    if (tid < 32) lp[tid] = lhs_pre[bt * 32 + tid];
    __syncthreads();
    for (int q = 0; q < 4; q++) {
        int n = q * 256 + tid;
        float a = 0.f;
        for (int f = 0; f < 32; f++) a += lp[f] * U2[f * NN + n];
        lhs[(size_t)bt * NN + n] = a;
    }
}

__global__ __launch_bounds__(64) void k_prod(const float* __restrict__ lhs,
                                             const float* __restrict__ rhs,
                                             float* __restrict__ prod)
{
    int blk = blockIdx.x;
    int b = blk / 144, r = blk - b * 144;
    int s = r / 12, u = r - s * 12;
    int tid = threadIdx.x;
    float p = 0.f;
    for (int n = tid; n < NN; n += 64)
        p += lhs[((size_t)b * 12 + s) * NN + n] * rhs[((size_t)b * NN + n) * 12 + u];
    for (int o = 32; o > 0; o >>= 1) p += __shfl_xor(p, o);
    if (tid == 0) prod[blk] = p;
}

// E (softmax over t) + EW1[b][t] = sum_u E[b,t,u]*W1[u]
__global__ __launch_bounds__(192) void k_E(const float* __restrict__ prod,
                                           const float* __restrict__ be,
                                           const float* __restrict__ Ve,
                                           const float* __restrict__ W1,
                                           float* __restrict__ E,
                                           float* __restrict__ EW1)
{
    int b = blockIdx.x, tid = threadIdx.x;
    __shared__ float ssig[144], sE[144], mx[12], sm[12];
    if (tid < 144) ssig[tid] = 1.f / (1.f + expf(-(prod[b * 144 + tid] + be[tid])));
    __syncthreads();
    if (tid < 144) {
        int t = tid / 12, u = tid - t * 12;
        float a = 0.f;
        for (int s2 = 0; s2 < 12; s2++) a += Ve[t * 12 + s2] * ssig[s2 * 12 + u];
        sE[tid] = a;
    }
    __syncthreads();
    if (tid < 12) {
        float m = -1e30f;
        for (int t = 0; t < 12; t++) m = fmaxf(m, sE[t * 12 + tid]);
        float s = 0.f;
        for (int t = 0; t < 12; t++) s += expf(sE[t * 12 + tid] - m);
        mx[tid] = m; sm[tid] = s;
    }
    __syncthreads();
    float val = 0.f;
    if (tid < 144) {
        int u = tid % 12;
        val = expf(sE[tid] - mx[u]) / sm[u];
        E[b * 144 + tid] = val;
    }
    __syncthreads();
    if (tid < 144) sE[tid] = val;
    __syncthreads();
    if (tid < 12) {
        float a = 0.f;
        for (int u = 0; u < 12; u++) a += sE[tid * 12 + u] * W1[u];
        EW1[b * 12 + tid] = a;
    }
}

// ---------------- l2/r2 directly from x (x_TAt eliminated) ----------------
// l2[b,n,u] = sum_f (sum_t x[b,n,f,t]*EW1[b,t]) * W2[f,u]
// r2[b,u,n] = sum_t rr3[b,n,t]*E[b,t,u]
__global__ __launch_bounds__(384) void k_l2r2x(const float* __restrict__ x,
                                               const float* __restrict__ rr3,
                                               const float* __restrict__ E,
                                               const float* __restrict__ EW1,
                                               const float* __restrict__ W2,
                                               float* __restrict__ l2,
                                               float* __restrict__ r2)
{
    __shared__ float xs[8 * 384];
    __shared__ float Es[144], ew[12], rrs[96], lp[8][32];
    int b = blockIdx.y, tid = threadIdx.x;
    int n0 = blockIdx.x * 8;
    size_t r0 = (size_t)b * NN + n0;
    if (tid < 144) Es[tid] = E[b * 144 + tid];
    if (tid < 12) ew[tid] = EW1[b * 12 + tid];
    if (tid < 96) rrs[tid] = rr3[(r0 + tid / 12) * 12 + (tid % 12)];
    for (int i = 0; i < 8; i++) xs[i * 384 + tid] = x[(r0 + i) * 384 + tid];
    __syncthreads();
    if (tid < 256) {
        int i = tid >> 5, f = tid & 31;
        float a = 0.f;
#pragma unroll
        for (int t = 0; t < 12; t++) a += xs[i * 384 + f * 12 + t] * ew[t];
        lp[i][f] = a;
    }
    __syncthreads();
    if (tid < 96) {
        int i = tid / 12, u = tid - i * 12;
        float a = 0.f;
        for (int f = 0; f < 32; f++) a += lp[i][f] * W2[f * 12 + u];
        l2[(r0 + i) * 12 + u] = a;
        float rv = 0.f;
#pragma unroll
        for (int t = 0; t < 12; t++) rv += rrs[i * 12 + t] * Es[t * 12 + u];
        r2[((size_t)b * 12 + u) * NN + n0 + i] = rv;
    }
}

// bs_t[k][m] = bs[m][k]
__global__ __launch_bounds__(256) void k_tbs(const float* __restrict__ bsin,
                                             float* __restrict__ bst)
{
    __shared__ float tl[64][65];
    int m0 = blockIdx.y * 64, k0 = blockIdx.x * 64;
    int tid = threadIdx.x;
    int c = tid & 63, r0 = tid >> 6;
    for (int i = 0; i < 16; i++) {
        int r = r0 + i * 4;
        tl[r][c] = bsin[(size_t)(m0 + r) * NN + k0 + c];
    }
    __syncthreads();
    for (int i = 0; i < 16; i++) {
        int r = r0 + i * 4;
        bst[(size_t)(k0 + r) * NN + m0 + c] = tl[c][r];
    }
}

// P_t[b][k][m] = bf16(sigmoid(sum_t l2[b,m,t]*r2[b,t,k] + bs[m,k]))
__global__ __launch_bounds__(256) void k_P_t(const float* __restrict__ l2,
                                             const float* __restrict__ r2,
                                             const float* __restrict__ bst,
                                             unsigned short* __restrict__ Pt)
{
    int b = blockIdx.y, k = blockIdx.x;
    int tid = threadIdx.x;
    float rv[12];
#pragma unroll
    for (int t = 0; t < 12; t++) rv[t] = r2[((size_t)b * 12 + t) * NN + k];
    for (int q = 0; q < 4; q++) {
        int m = q * 256 + tid;
        const float* lp = &l2[((size_t)b * NN + m) * 12];
        float p = 0.f;
#pragma unroll
        for (int t = 0; t < 12; t++) p += lp[t] * rv[t];
        p += bst[(size_t)k * NN + m];
        float sg = 1.f / (1.f + expf(-p));
        Pt[((size_t)b * NN + k) * NN + m] = cvt_bf(sg);
    }
}

// Vs fp32 -> bf16
__global__ __launch_bounds__(256) void k_cvt(const float* __restrict__ s,
                                             unsigned short* __restrict__ d)
{
    size_t i = ((size_t)blockIdx.x * 256 + threadIdx.x) * 4;
    float4 v = *(const float4*)(s + i);
    unsigned int p0 = (unsigned int)cvt_bf(v.x) | ((unsigned int)cvt_bf(v.y) << 16);
    unsigned int p1 = (unsigned int)cvt_bf(v.z) | ((unsigned int)cvt_bf(v.w) << 16);
    *(unsigned int*)(d + i) = p0;
    *(unsigned int*)(d + i + 2) = p1;
}

// bf16 transpose 1024x1024
__global__ __launch_bounds__(256) void k_tb16(const unsigned short* __restrict__ s,
                                              unsigned short* __restrict__ d)
{
    __shared__ unsigned short tl[64][65];
    int r0 = blockIdx.y * 64, c0 = blockIdx.x * 64;
    int tid = threadIdx.x;
    int c = tid & 63, rr = tid >> 6;
    for (int i = 0; i < 16; i++)
        tl[rr + i * 4][c] = s[(size_t)(r0 + rr + i * 4) * NN + c0 + c];
    __syncthreads();
    for (int i = 0; i < 16; i++)
        d[(size_t)(c0 + rr + i * 4) * NN + r0 + c] = tl[c][rr + i * 4];
}

// ---------------- MFMA bf16 NT GEMM ----------------
// MODE 1: bf16 out. MODE 2: fp32 exp(out) + colsum atomics. MODE 3: split-K fp32 atomicAdd (bz = k-chunk).
template<int MODE>
__global__ __launch_bounds__(256) void mgemm(const short* __restrict__ A,
                                             const short* __restrict__ B,
                                             void* __restrict__ Cv,
                                             int Kd, int kchunk,
                                             int ldA, int ldB, int ldC,
                                             long sA, long sB, long sC,
                                             float* __restrict__ colsum)
{
    int bz = blockIdx.z;
    const short* Ab = A + (size_t)bz * sA;
    const short* Bb = B + (size_t)bz * sB;
    int i0 = blockIdx.y * 128, j0 = blockIdx.x * 128;
    __shared__ short sm[16384];            // As [128][64] @0, Bs [128][64] @8192
    int tid = threadIdx.x;
    int ln = tid & 63, wv = tid >> 6;
    int wm = (wv >> 1) * 64, wn = (wv & 1) * 64;
    int fr = ln & 15, fk = ln >> 4;
    f32x4 acc[4][4];
#pragma unroll
    for (int a = 0; a < 4; a++)
#pragma unroll
        for (int b2 = 0; b2 < 4; b2++) acc[a][b2] = (f32x4)(0.f);

    int k_lo = 0, k_hi = Kd;
    if constexpr (MODE == 3) { k_lo = bz * kchunk; k_hi = k_lo + kchunk; }

    for (int k0 = k_lo; k0 < k_hi; k0 += 64) {
#pragma unroll
        for (int q = 0; q < 4; q++) {
            int e = q * 2048 + tid * 8;
            const short* src = Ab + (size_t)(i0 + (e >> 6)) * ldA + k0 + (e & 63);
            gll16(src, sm + e);
        }
#pragma unroll
        for (int q = 0; q < 4; q++) {
            int e = q * 2048 + tid * 8;
            const short* src = Bb + (size_t)(j0 + (e >> 6)) * ldB + k0 + (e & 63);
            gll16(src, sm + 8192 + e);
        }
        __syncthreads();
#pragma unroll
        for (int ks = 0; ks < 2; ks++) {
            bf16x8 av[4], bv[4];
#pragma unroll
            for (int mi = 0; mi < 4; mi++)
                av[mi] = *(const bf16x8*)(sm + (wm + mi * 16 + fr) * 64 + ks * 32 + fk * 8);
#pragma unroll
            for (int nj = 0; nj < 4; nj++)
                bv[nj] = *(const bf16x8*)(sm + 8192 + (wn + nj * 16 + fr) * 64 + ks * 32 + fk * 8);
#pragma unroll
            for (int mi = 0; mi < 4; mi++)
#pragma unroll
                for (int nj = 0; nj < 4; nj++)
                    acc[mi][nj] = __builtin_amdgcn_mfma_f32_16x16x32_bf16(av[mi], bv[nj], acc[mi][nj], 0, 0, 0);
        }
        __syncthreads();
    }
    if constexpr (MODE == 2) {
        float* Cb = (float*)Cv + (size_t)bz * sC;
#pragma unroll
        for (int nj = 0; nj < 4; nj++) {
            float cs = 0.f;
            int col = j0 + wn + nj * 16 + fr;
#pragma unroll
            for (int mi = 0; mi < 4; mi++) {
                int row = i0 + wm + mi * 16 + fk * 4;
#pragma unroll
                for (int r = 0; r < 4; r++) {
                    float e = expf(acc[mi][nj][r]);
                    Cb[(size_t)(row + r) * ldC + col] = e;
                    cs += e;
                }
            }
            cs += __shfl_xor(cs, 16);
            cs += __shfl_xor(cs, 32);
            if (ln < 16) atomicAdd(&colsum[(size_t)bz * NN + col], cs);
        }
    } else if constexpr (MODE == 3) {
        float* Cb = (float*)Cv;
#pragma unroll
        for (int mi = 0; mi < 4; mi++)
#pragma unroll
            for (int nj = 0; nj < 4; nj++) {
                int row = i0 + wm + mi * 16 + fk * 4;
                int col = j0 + wn + nj * 16 + fr;
#pragma unroll
                for (int r = 0; r < 4; r++)
                    atomicAdd(&Cb[(size_t)(row + r) * ldC + col], acc[mi][nj][r]);
            }
    } else {
#pragma unroll
        for (int mi = 0; mi < 4; mi++)
#pragma unroll
            for (int nj = 0; nj < 4; nj++) {
                int row = i0 + wm + mi * 16 + fk * 4;
                int col = j0 + wn + nj * 16 + fr;
                unsigned short* Cb = (unsigned short*)Cv + (size_t)bz * sC;
#pragma unroll
                for (int r = 0; r < 4; r++)
                    Cb[(size_t)(row + r) * ldC + col] = cvt_bf(acc[mi][nj][r]);
            }
    }
}

// ---------------- normalize + threshold + At1 + At2 (fully fused) ----------------
// spat holds exp(S); out: spat = thresholded Sn;
// At1[b][m][n] = bf16(sup[n][m]*Sn[n][m]); At2[b][m][n] = bf16((2*supsq[n][m]-d_nm)*Sn[n][m])
__global__ __launch_bounds__(256) void k_normprep2(float* __restrict__ spat,
                                                   const float* __restrict__ colsum,
                                                   const float* __restrict__ sup,
                                                   const float* __restrict__ supsq,
                                                   unsigned short* __restrict__ At1,
                                                   unsigned short* __restrict__ At2)
{
    __shared__ unsigned short t1[64][66];
    __shared__ unsigned short t2[64][66];
    int b = blockIdx.z;
    int n0 = blockIdx.y * 64, m0 = blockIdx.x * 64;
    int tid = threadIdx.x;
    int c = tid & 63, r0 = tid >> 6;
    const float thr = (1.0f / 1024.0f) / 0.6f;
    float inv = 1.f / colsum[(size_t)b * NN + m0 + c];
    float* sp = spat + (size_t)b * NN * NN;
    for (int i = 0; i < 16; i++) {
        int r = r0 + i * 4;
        size_t idx = (size_t)(n0 + r) * NN + m0 + c;
        float v = sp[idx] * inv;
        v = (v < thr) ? 0.f : v;
        sp[idx] = v;
        t1[r][c] = cvt_bf(sup[(size_t)(n0 + r) * NN + m0 + c] * v);
        float p2 = 2.f * supsq[(size_t)(n0 + r) * NN + m0 + c]
                 - (((n0 + r) == (m0 + c)) ? 1.f : 0.f);
        t2[r][c] = cvt_bf(p2 * v);
    }
    __syncthreads();
    int c2 = tid & 31, r4 = tid >> 5;
    size_t ob = ((size_t)b * NN + m0) * NN + n0;
    for (int i = 0; i < 8; i++) {
        int rr = r4 + i * 8;
        unsigned int v1 = (unsigned int)t1[2 * c2][rr] | ((unsigned int)t1[2 * c2 + 1][rr] << 16);
        unsigned int v2 = (unsigned int)t2[2 * c2][rr] | ((unsigned int)t2[2 * c2 + 1][rr] << 16);
        *(unsigned int*)(At1 + ob + (size_t)rr * NN + 2 * c2) = v1;
        *(unsigned int*)(At2 + ob + (size_t)rr * NN + 2 * c2) = v2;
    }
}

// ---------------- support graph (fp32 + bf16 copies) ----------------
__global__ __launch_bounds__(256) void k_sup(const float* __restrict__ emb,
                                             float* __restrict__ sup,
                                             unsigned short* __restrict__ supB)
{
    int n = blockIdx.x, tid = threadIdx.x;
    __shared__ float en[16];
    if (tid < 16) en[tid] = emb[n * 16 + tid];
    __syncthreads();
    float v[4];
#pragma unroll
    for (int q = 0; q < 4; q++) {
        int m = q * 256 + tid;
        float d = 0.f;
#pragma unroll
        for (int dd = 0; dd < 16; dd++) d += en[dd] * emb[m * 16 + dd];
        v[q] = fmaxf(d, 0.f);
    }
    float mx = fmaxf(fmaxf(v[0], v[1]), fmaxf(v[2], v[3]));
    for (int o = 32; o > 0; o >>= 1) mx = fmaxf(mx, __shfl_xor(mx, o));
    __shared__ float red[4];
    if ((tid & 63) == 0) red[tid >> 6] = mx;
    __syncthreads();
    mx = fmaxf(fmaxf(red[0], red[1]), fmaxf(red[2], red[3]));
    float e[4];
    float s = 0.f;
#pragma unroll
    for (int q = 0; q < 4; q++) { e[q] = expf(v[q] - mx); s += e[q]; }
    for (int o = 32; o > 0; o >>= 1) s += __shfl_xor(s, o);
    __shared__ float red2[4];
    if ((tid & 63) == 0) red2[tid >> 6] = s;
    __syncthreads();
    s = red2[0] + red2[1] + red2[2] + red2[3];
    float inv = 1.f / s;
#pragma unroll
    for (int q = 0; q < 4; q++) {
        float val = e[q] * inv;
        sup[(size_t)n * NN + q * 256 + tid] = val;
        supB[(size_t)n * NN + q * 256 + tid] = cvt_bf(val);
    }
}

// Xt[b][j][n] = bf16(x[b][n][j])
__global__ __launch_bounds__(256) void k_xt(const float* __restrict__ x,
                                            unsigned short* __restrict__ Xt)
{
    __shared__ float tl[64][65];
    int b = blockIdx.z;
    int n0 = blockIdx.y * 64, j0 = blockIdx.x * 64;
    int tid = threadIdx.x;
    int c = tid & 63, r0 = tid >> 6;
    for (int i = 0; i < 16; i++) {
        int r = r0 + i * 4;
        tl[r][c] = x[((size_t)b * NN + n0 + r) * 384 + j0 + c];
    }
    __syncthreads();
    int c2 = tid & 31, r4 = tid >> 5;
    unsigned short* ob = Xt + ((size_t)b * 384 + j0) * NN + n0;
    for (int i = 0; i < 8; i++) {
        int jj = r4 + i * 8;
        unsigned int v0 = cvt_bf(tl[2 * c2][jj]);
        unsigned int v1 = cvt_bf(tl[2 * c2 + 1][jj]);
        *(unsigned int*)(ob + (size_t)jj * NN + 2 * c2) = v0 | (v1 << 16);
    }
}

// ---------------- weight prep ----------------
__global__ __launch_bounds__(192) void k_wnorm(const float* __restrict__ tcv,
                                               const float* __restrict__ tcg,
                                               unsigned short* __restrict__ Wr)
{
    int o = blockIdx.x, tid = threadIdx.x;
    float t = tcv[o * 192 + tid];
    float p = t * t;
    for (int off = 32; off > 0; off >>= 1) p += __shfl_xor(p, off);
    __shared__ float wsr[3];
    if ((tid & 63) == 0) wsr[tid >> 6] = p;
    __syncthreads();
    float sum = wsr[0] + wsr[1] + wsr[2];
    int c = tid / 3, dt = tid - c * 3;
    Wr[o * 192 + dt * 64 + c] = cvt_bf(t * (tcg[o] / sqrtf(sum)));
}

__global__ __launch_bounds__(256) void k_prepw(const float* __restrict__ Theta,
                                               const float* __restrict__ rcw,
                                               unsigned short* __restrict__ Th,
                                               unsigned short* __restrict__ Rc)
{
    int tid = threadIdx.x;
    for (int i = tid; i < 6144; i += 256) {
        int o = i / 96, rem = i - o * 96;
        int kind = rem >> 5, f = rem & 31;
        Th[i] = cvt_bf(Theta[kind * 2048 + f * 64 + o]);
    }
    for (int i = tid; i < 2048; i += 256) Rc[i] = cvt_bf(rcw[i]);
}

// ---------------- MFMA fused tail ----------------
__global__ __launch_bounds__(256) void k_tail(const float* __restrict__ x,
                                              const unsigned short* __restrict__ h1,
                                              const unsigned short* __restrict__ h2,
                                              const float* __restrict__ spat,
                                              const unsigned short* __restrict__ Th,
                                              const unsigned short* __restrict__ Wr,
                                              const unsigned short* __restrict__ Rc,
                                              const float* __restrict__ tcb,
                                              const float* __restrict__ rcb,
                                              const float* __restrict__ lnw,
                                              const float* __restrict__ lnb,
                                              float* __restrict__ out)
{
    int b = blockIdx.y;
    int node0 = blockIdx.x * 8;
    int tid = threadIdx.x;
    int ln = tid & 63, wv = tid >> 6;
    int fr = ln & 15, fk = ln >> 4;

    __shared__ union {
        struct { unsigned short xt[3840], h1t[3840], h2t[3840], gcn[8064]; } a;
        float Y[96 * 65];
    } u;
    __shared__ float sdp[96];
    __shared__ float lnwS[64], lnbS[64], tbS[64];
    __shared__ float muS[96], rsS[96];

    size_t rowb = ((size_t)b * NN + node0) * 384;
    for (int i = tid; i < 3072; i += 256) {
        int node = i / 384, j = i - node * 384;
        int f = j / 12, t = j - f * 12;
        int la = node * 480 + t * 40 + f;
        u.a.xt[la]  = cvt_bf(x[rowb + i]);
        u.a.h1t[la] = h1[rowb + i];
        u.a.h2t[la] = h2[rowb + i];
    }
    for (int i = tid; i < 1152; i += 256) {
        int node = i / 144, r = i - node * 144;
        int rr = (r < 72) ? 0 : 13;
        u.a.gcn[node * 1008 + rr * 72 + (r % 72)] = 0;
    }
    if (tid < 96) {
        int node = tid / 12;
        sdp[tid] = spat[(size_t)b * NN * NN + (size_t)(node0 + node) * NN + node0 + node];
    }
    if (tid < 64) { lnwS[tid] = lnw[tid]; lnbS[tid] = lnb[tid]; tbS[tid] = tcb[tid] + rcb[tid]; }

    int ocol = wv * 16 + fr;
    bf16x8 bTh[3], bWr[6], bRc;
#pragma unroll
    for (int kb = 0; kb < 3; kb++)
        bTh[kb] = *(const bf16x8*)((const short*)Th + (size_t)ocol * 96 + kb * 32 + fk * 8);
#pragma unroll
    for (int kb = 0; kb < 6; kb++)
        bWr[kb] = *(const bf16x8*)((const short*)Wr + (size_t)ocol * 192 + kb * 32 + fk * 8);
    bRc = *(const bf16x8*)((const short*)Rc + (size_t)ocol * 32 + fk * 8);

    int na[6], ta[6];
#pragma unroll
    for (int rb = 0; rb < 6; rb++) {
        int p = rb * 16 + fr;
        na[rb] = p / 12; ta[rb] = p - na[rb] * 12;
    }
    __syncthreads();

    f32x4 acc[6];
#pragma unroll
    for (int rb = 0; rb < 6; rb++) {
        int ax = na[rb] * 480 + ta[rb] * 40 + fk * 8;
        bf16x8 avx = *(const bf16x8*)(u.a.xt + ax);
        f32x4 z = (f32x4)(0.f);
        acc[rb] = __builtin_amdgcn_mfma_f32_16x16x32_bf16(avx, bTh[0], z, 0, 0, 0);
#pragma unroll
        for (int r = 0; r < 4; r++) acc[rb][r] *= sdp[rb * 16 + fk * 4 + r];
        bf16x8 av1 = *(const bf16x8*)(u.a.h1t + ax);
        acc[rb] = __builtin_amdgcn_mfma_f32_16x16x32_bf16(av1, bTh[1], acc[rb], 0, 0, 0);
        bf16x8 av2 = *(const bf16x8*)(u.a.h2t + ax);
        acc[rb] = __builtin_amdgcn_mfma_f32_16x16x32_bf16(av2, bTh[2], acc[rb], 0, 0, 0);
    }
#pragma unroll
    for (int rb = 0; rb < 6; rb++) {
#pragma unroll
        for (int r = 0; r < 4; r++) {
            int pc = rb * 16 + fk * 4 + r;
            int nc = pc / 12, tc2 = pc - nc * 12;
            u.a.gcn[nc * 1008 + (tc2 + 1) * 72 + wv * 16 + fr] = cvt_bf(fmaxf(acc[rb][r], 0.f));
        }
    }
    __syncthreads();
#pragma unroll
    for (int rb = 0; rb < 6; rb++) {
        f32x4 a2 = (f32x4)(0.f);
#pragma unroll
        for (int kb = 0; kb < 6; kb++) {
            int dt = kb >> 1, c0 = (kb & 1) * 32;
            bf16x8 ag = *(const bf16x8*)(u.a.gcn + na[rb] * 1008 + (ta[rb] + dt) * 72 + c0 + fk * 8);
            a2 = __builtin_amdgcn_mfma_f32_16x16x32_bf16(ag, bWr[kb], a2, 0, 0, 0);
        }
        int ax = na[rb] * 480 + ta[rb] * 40 + fk * 8;
        bf16x8 avx = *(const bf16x8*)(u.a.xt + ax);
        acc[rb] = __builtin_amdgcn_mfma_f32_16x16x32_bf16(avx, bRc, a2, 0, 0, 0);
    }
    __syncthreads();
    float tb = tbS[ocol];
#pragma unroll
    for (int rb = 0; rb < 6; rb++)
#pragma unroll
        for (int r = 0; r < 4; r++)
            u.Y[(rb * 16 + fk * 4 + r) * 65 + ocol] = acc[rb][r] + tb;
    __syncthreads();
    if (tid < 96) {
        float s = 0.f, s2 = 0.f;
        for (int o = 0; o < 64; o++) {
            float v = u.Y[tid * 65 + o];
            s += v; s2 += v * v;
        }
        float mm = s * (1.f / 64.f);
        float var = s2 * (1.f / 64.f) - mm * mm;
        muS[tid] = mm; rsS[tid] = rsqrtf(var + 1e-5f);
    }
    __syncthreads();
    float* ob = out + rowb * 2;
    for (int i = tid; i < 6144; i += 256) {
        int node = i / 768, rr = i - node * 768;
        int o = rr / 12, t = rr - o * 12;
        int p = node * 12 + t;
        ob[i] = (u.Y[p * 65 + o] - muS[p]) * rsS[p] * lnwS[o] + lnbS[o];
    }
}

extern "C" void kernel_launch(void* const* d_in, const int* in_sizes, int n_in,
                              void* d_out, int out_size, void* d_ws, size_t ws_size,
                              hipStream_t stream)
{
    const float* x    = (const float*)d_in[0];
    const float* emb  = (const float*)d_in[1];
    const float* W1   = (const float*)d_in[2];
    const float* W2   = (const float*)d_in[3];
    const float* W3   = (const float*)d_in[4];
    const float* bs   = (const float*)d_in[5];
    const float* Vs   = (const float*)d_in[6];
    const float* U1   = (const float*)d_in[7];
    const float* U2   = (const float*)d_in[8];
    const float* U3   = (const float*)d_in[9];
    const float* be   = (const float*)d_in[10];
    const float* Ve   = (const float*)d_in[11];
    const float* Theta= (const float*)d_in[12];
    const float* tcv  = (const float*)d_in[13];
    const float* tcg  = (const float*)d_in[14];
    const float* tcb  = (const float*)d_in[15];
    const float* rcw  = (const float*)d_in[16];
    const float* rcb  = (const float*)d_in[17];
    const float* lnw  = (const float*)d_in[18];
    const float* lnb  = (const float*)d_in[19];

    float* xres = (float*)d_out;                       // B*N*FT*T fp32 (scratch for At2 until k_tail)
    float* spat = xres + (size_t)NB * NN * NFT * NT;   // B*N*N fp32

    char* base = (char*)d_ws;
    unsigned short* Pt   = (unsigned short*)(base + 0);   // then supB/supT, then At1
    unsigned short* supB = (unsigned short*)(base + 0);
    unsigned short* supT = (unsigned short*)(base + 2097152);
    unsigned short* At1  = (unsigned short*)(base + 0);
    unsigned short* At2  = (unsigned short*)xres;          // d_out scratch (32 MB < 48 MB)
    unsigned short* Xt  = (unsigned short*)(base + 33554432);
    unsigned short* h1  = (unsigned short*)(base + 46137344);
    unsigned short* h2  = (unsigned short*)(base + 58720256);
    unsigned short* Vsb = (unsigned short*)(base + 71303168);
    float* bst     = (float*)(base + 73400320);           // dead after k_P_t
    float* colsum  = (float*)(base + 73400320);           // reuses bst region
    float* sup     = (float*)(base + 77594624);
    float* supsq   = (float*)(base + 81788928);
    float* lhs_pre = (float*)(base + 85983232);
    float* lhs     = (float*)(base + 86007808);
    float* rhs     = (float*)(base + 86794240);
    float* rr3     = (float*)(base + 87580672);
    float* prod    = (float*)(base + 88367104);
    float* E       = (float*)(base + 88376320);
    float* EW1     = (float*)(base + 88385536);
    float* l2      = (float*)(base + 88386560);
    float* r2      = (float*)(base + 89172992);
    unsigned short* Wr = (unsigned short*)(base + 89959424);
    unsigned short* Th = (unsigned short*)(base + 89984000);
    unsigned short* Rc = (unsigned short*)(base + 89996288);

    hipMemsetAsync(lhs_pre, 0, 6144 * sizeof(float), stream);
    hipMemsetAsync(supsq, 0, (size_t)NN * NN * sizeof(float), stream);

    // temporal attention
    k_pre<<<dim3(16, 16), 384, 0, stream>>>(x, U1, U3, W3, lhs_pre, rhs, rr3);
    k_lhs<<<192, 256, 0, stream>>>(lhs_pre, U2, lhs);
    k_prod<<<2304, 64, 0, stream>>>(lhs, rhs, prod);
    k_E<<<16, 192, 0, stream>>>(prod, be, Ve, W1, E, EW1);
    // spatial attention (x_TAt eliminated algebraically)
    k_l2r2x<<<dim3(128, 16), 384, 0, stream>>>(x, rr3, E, EW1, W2, l2, r2);
    k_tbs<<<dim3(16, 16), 256, 0, stream>>>(bs, bst);
    k_P_t<<<dim3(1024, 16), 256, 0, stream>>>(l2, r2, bst, Pt);
    k_cvt<<<1024, 256, 0, stream>>>(Vs, Vsb);
    hipMemsetAsync(colsum, 0, (size_t)NB * NN * sizeof(float), stream);  // bst dead now
    mgemm<2><<<dim3(8, 8, 16), 256, 0, stream>>>((const short*)Vsb, (const short*)Pt,
        (void*)spat, NN, 0, NN, NN, NN, 0L, (long)NN * NN, (long)NN * NN, colsum);
    // graph supports
    k_sup<<<1024, 256, 0, stream>>>(emb, sup, supB);
    k_tb16<<<dim3(16, 16), 256, 0, stream>>>(supB, supT);
    mgemm<3><<<dim3(8, 8, 4), 256, 0, stream>>>((const short*)supB, (const short*)supT,
        (void*)supsq, NN, 256, NN, NN, NN, 0L, 0L, 0L, nullptr);
    // normalize + threshold + both masked adjacencies, one pass
    k_normprep2<<<dim3(16, 16, 16), 256, 0, stream>>>(spat, colsum, sup, supsq, At1, At2);
    k_xt<<<dim3(6, 16, 16), 256, 0, stream>>>(x, Xt);
    mgemm<1><<<dim3(3, 8, 16), 256, 0, stream>>>((const short*)At1, (const short*)Xt,
        (void*)h1, NN, 0, NN, NN, 384, (long)NN * NN, 384L * NN, (long)NN * 384, nullptr);
    mgemm<1><<<dim3(3, 8, 16), 256, 0, stream>>>((const short*)At2, (const short*)Xt,
        (void*)h2, NN, 0, NN, NN, 384, (long)NN * NN, 384L * NN, (long)NN * 384, nullptr);
    // tail
    k_wnorm<<<64, 192, 0, stream>>>(tcv, tcg, Wr);
    k_prepw<<<1, 256, 0, stream>>>(Theta, rcw, Th, Rc);
    k_tail<<<dim3(128, 16), 256, 0, stream>>>(x, h1, h2, spat, Th, Wr, Rc,
                                              tcb, rcb, lnw, lnb, xres);
}